// Round 18
// baseline (233.469 us; speedup 1.0000x reference)
//
#include <hip/hip_runtime.h>
#include <stdint.h>
#include <stddef.h>

typedef __bf16 bf16;
typedef __bf16 bf16x8 __attribute__((ext_vector_type(8)));
typedef __bf16 bf16x4 __attribute__((ext_vector_type(4)));
typedef float  f32x4  __attribute__((ext_vector_type(4)));
typedef uint32_t u32x4 __attribute__((ext_vector_type(4)));

#define MFMA(a, b, c) __builtin_amdgcn_mfma_f32_16x16x32_bf16((a), (b), (c), 0, 0, 0)
// element offset of (row, 16B-chunk) in a swizzled [*][64] bf16 tile
#define SWZE(row, chunk) (((row) << 6) + ((((chunk) ^ ((row) & 7))) << 3))

static __device__ __forceinline__ void gload_lds16(const void* g, void* l) {
  __builtin_amdgcn_global_load_lds((const __attribute__((address_space(1))) void*)g,
                                   (__attribute__((address_space(3))) void*)l,
                                   16, 0, 0);
}
static __device__ __forceinline__ void waitvm0() {
  asm volatile("s_waitcnt vmcnt(0)" ::: "memory");
}
static __device__ __forceinline__ float expq(float x) {  // raw v_exp_f32 (2^x)
  float r;
  asm("v_exp_f32 %0, %1" : "=v"(r) : "v"(x));
  return r;
}
static __device__ __forceinline__ float rcpq(float x) {
  float r;
  asm("v_rcp_f32 %0, %1" : "=v"(r) : "v"(x));
  return r;
}
static __device__ __forceinline__ uint32_t cvtpk_bf16(float lo, float hi) {
  uint32_t r;
  asm("v_cvt_pk_bf16_f32 %0, %1, %2" : "=v"(r) : "v"(lo), "v"(hi));
  return r;
}
// bijective XCD swizzle (requires nwg % 8 == 0)
static __device__ __forceinline__ int xcd_swz(int orig, int nwg) {
  return (orig & 7) * (nwg >> 3) + (orig >> 3);
}
// V^T k-permutation within each 32-block: staged slot t holds V row
// k_phys(t) = t2<<4 | t4<<3 | t3<<2 | t1<<1 | t0. Inverse (store side):
// row s goes to slot (s&~31) | s3<<4 | s2<<3 | s4<<2 | (s&3)
static __device__ __forceinline__ int vperm_store(int s) {
  return (s & ~31) | (((s >> 3) & 1) << 4) | (((s >> 2) & 1) << 3) |
         (((s >> 4) & 1) << 2) | (s & 3);
}

// ---------------------------------------------------------------------------
// prep_k: fused input-convert + all weight packing (one launch).
__global__ __launch_bounds__(256) void prep_k(
    const float* __restrict__ inp, const float* __restrict__ ctx,
    bf16* __restrict__ XB, bf16* __restrict__ CB,
    const float* __restrict__ Wq1, const float* __restrict__ Wk1,
    const float* __restrict__ Wv1, const float* __restrict__ Wq2,
    const float* __restrict__ Wk2, const float* __restrict__ Wv2,
    bf16* __restrict__ WQKV1, bf16* __restrict__ WQ2, bf16* __restrict__ WKV2,
    const float* __restrict__ Wo1, const float* __restrict__ Wo2,
    const float* __restrict__ Wf,
    bf16* __restrict__ WO1, bf16* __restrict__ WO2, bf16* __restrict__ WFt) {
  const int tid = threadIdx.x;
  int bx = blockIdx.x;
  if (bx < 8192) {
    const float* s = bx < 4096 ? inp : ctx;
    bf16* d = bx < 4096 ? XB : CB;
    size_t idx = (size_t)(bx & 4095) * 256 + tid;
    float4 v = *(const float4*)(s + idx * 4);
    bf16x4 o;
    o[0] = (bf16)v.x; o[1] = (bf16)v.y; o[2] = (bf16)v.z; o[3] = (bf16)v.w;
    *(bf16x4*)(d + idx * 4) = o;
    return;
  }
  bx -= 8192;
  __shared__ float T[64][65];
  if (bx < 1536) {
    const int wi = bx >> 8, sub = bx & 255;
    const float* src = (wi == 0) ? Wq1 : (wi == 1) ? Wk1 : (wi == 2) ? Wv1
                     : (wi == 3) ? Wq2 : (wi == 4) ? Wk2 : Wv2;
    bf16* dst = (wi == 0) ? WQKV1 : (wi == 1) ? WQKV1 + 1048576
              : (wi == 2) ? WQKV1 + 2097152 : (wi == 3) ? WQ2
              : (wi == 4) ? WKV2 : WKV2 + 1048576;
    const int e0 = (sub & 15) * 64, h = sub >> 4;
    const int er = tid >> 4, dof = (tid & 15) * 4;
#pragma unroll
    for (int i = 0; i < 4; ++i) {
      int e = i * 16 + er;
      float4 v = *(const float4*)(src + ((size_t)h * 1024 + e0 + e) * 64 + dof);
      T[e][dof] = v.x; T[e][dof + 1] = v.y; T[e][dof + 2] = v.z; T[e][dof + 3] = v.w;
    }
    __syncthreads();
    const int dr = tid >> 3, eo = (tid & 7) * 8;
#pragma unroll
    for (int i = 0; i < 2; ++i) {
      int d = i * 32 + dr;
      bf16x8 ov;
#pragma unroll
      for (int j = 0; j < 8; ++j) ov[j] = (bf16)T[eo + j][d];
      *(bf16x8*)(dst + ((size_t)h * 64 + d) * 1024 + e0 + eo) = ov;
    }
    return;
  }
  bx -= 1536;
  {
    const int wi = bx >> 8, sub = bx & 255;
    const float* src = (wi == 0) ? Wo1 : (wi == 1) ? Wo2 : Wf;
    bf16* dst = (wi == 0) ? WO1 : (wi == 1) ? WO2 : WFt;
    const int k0 = (sub & 15) * 64, n0 = (sub >> 4) * 64;
    const int kr = tid >> 4, no = (tid & 15) * 4;
#pragma unroll
    for (int i = 0; i < 4; ++i) {
      int k = i * 16 + kr;
      float4 v = *(const float4*)(src + (size_t)(k0 + k) * 1024 + n0 + no);
      T[k][no] = v.x; T[k][no + 1] = v.y; T[k][no + 2] = v.z; T[k][no + 3] = v.w;
    }
    __syncthreads();
    const int nr = tid >> 3, ko = (tid & 7) * 8;
#pragma unroll
    for (int i = 0; i < 2; ++i) {
      int n = i * 32 + nr;
      bf16x8 ov;
#pragma unroll
      for (int j = 0; j < 8; ++j) ov[j] = (bf16)T[ko + j][n];
      *(bf16x8*)(dst + (size_t)(n0 + n) * 1024 + k0 + ko) = ov;
    }
  }
}

// ---------------------------------------------------------------------------
// 128x128 GEMM body, XOR-swizzled LDS tiles (conflict-free ds_read_b128).
template <int EPI>
static __device__ __forceinline__ void gemm_body(
    const bf16* __restrict__ A, const bf16* __restrict__ Bt,
    bf16* __restrict__ Cb, float* __restrict__ Cf,
    const float* __restrict__ bias, const float* __restrict__ resid,
    int N, int K, float mul, int m0, int n0, bf16* As, bf16* Bs,
    bf16* __restrict__ Vt, int colV) {
  const int tid = threadIdx.x;
  const int l = tid & 63, w = tid >> 6;
  const int l15 = l & 15, g4 = l >> 4;
  const int wr = w >> 1, wc = w & 1;
  f32x4 acc[4][4] = {};
  const int crow = tid >> 3, sj = tid & 7;
  for (int k0 = 0; k0 < K; k0 += 64) {
#pragma unroll
    for (int i = 0; i < 4; ++i) {
      int row = i * 32 + crow;
      int je = ((sj ^ (row & 7)) << 3);   // pre-swizzled source chunk
      gload_lds16(A + (size_t)(m0 + row) * K + (k0 + je), (char*)As + (i * 256 + tid) * 16);
      gload_lds16(Bt + (size_t)(n0 + row) * K + (k0 + je), (char*)Bs + (i * 256 + tid) * 16);
    }
    __syncthreads();
#pragma unroll
    for (int kk = 0; kk < 2; ++kk) {
      bf16x8 af[4], bfr[4];
#pragma unroll
      for (int x = 0; x < 4; ++x) {
        af[x]  = *(const bf16x8*)&As[SWZE(wr * 64 + x * 16 + l15, kk * 4 + g4)];
        bfr[x] = *(const bf16x8*)&Bs[SWZE(wc * 64 + x * 16 + l15, kk * 4 + g4)];
      }
      __builtin_amdgcn_s_setprio(1);
#pragma unroll
      for (int mf = 0; mf < 4; ++mf)
#pragma unroll
        for (int nf = 0; nf < 4; ++nf)
          acc[mf][nf] = MFMA(af[mf], bfr[nf], acc[mf][nf]);
      __builtin_amdgcn_s_setprio(0);
    }
    __syncthreads();
  }
  if (EPI == 2 && n0 >= colV) {
#pragma unroll
    for (int mf = 0; mf < 4; ++mf)
#pragma unroll
      for (int nf = 0; nf < 4; ++nf) {
        int colrel = n0 + wc * 64 + nf * 16 + l15 - colV;
        int h = colrel >> 6, d = colrel & 63;
        int row = m0 + wr * 64 + mf * 16 + g4 * 4;
        int b = row >> 11, s = row & 2047;
        bf16x4 pv;
#pragma unroll
        for (int r = 0; r < 4; ++r) pv[r] = (bf16)acc[mf][nf][r];
        *(bf16x4*)(Vt + (((size_t)(b * 16 + h) * 64 + d) * 2048 + vperm_store(s))) = pv;
      }
    return;
  }
#pragma unroll
  for (int mf = 0; mf < 4; ++mf)
#pragma unroll
    for (int nf = 0; nf < 4; ++nf)
#pragma unroll
      for (int r = 0; r < 4; ++r) {
        int row = m0 + wr * 64 + mf * 16 + g4 * 4 + r;
        int col = n0 + wc * 64 + nf * 16 + l15;
        size_t idx = (size_t)row * N + col;
        float v = acc[mf][nf][r];
        if (EPI == 1) {
          v = mul * fmaxf(v + bias[col], 0.f);
          if (resid) v += resid[idx];
          Cf[idx] = v;
        } else {
          Cb[idx] = (bf16)v;
        }
      }
}

// QKV projection GEMM (N=3072), V block-columns written transposed to Vt
__global__ __launch_bounds__(256) void gemm_qkv_k(
    const bf16* __restrict__ A, const bf16* __restrict__ Bt,
    bf16* __restrict__ Cb, bf16* __restrict__ Vt, int N, int K, int colV) {
  __shared__ __align__(16) bf16 As[128 * 64];
  __shared__ __align__(16) bf16 Bs[128 * 64];
  int swz = xcd_swz(blockIdx.y * gridDim.x + blockIdx.x, gridDim.x * gridDim.y);
  int bx = swz % gridDim.x, by = swz / gridDim.x;
  gemm_body<2>(A, Bt, Cb, nullptr, nullptr, nullptr, N, K, 1.f,
               by * 128, bx * 128, As, Bs, Vt, colV);
}

// Merged dispatch for layer 2: x<8 -> Q2 (N=1024), else KV2 (N=2048, V->V2T)
__global__ __launch_bounds__(256) void gemm_bt2_k(
    const bf16* __restrict__ A0, const bf16* __restrict__ Bt0, bf16* __restrict__ C0,
    const bf16* __restrict__ A1, const bf16* __restrict__ Bt1, bf16* __restrict__ C1,
    bf16* __restrict__ Vt, int K) {
  __shared__ __align__(16) bf16 As[128 * 64];
  __shared__ __align__(16) bf16 Bs[128 * 64];
  int swz = xcd_swz(blockIdx.y * gridDim.x + blockIdx.x, gridDim.x * gridDim.y);
  int bx = swz % gridDim.x, by = swz / gridDim.x;
  if (bx < 8)
    gemm_body<0>(A0, Bt0, C0, nullptr, nullptr, nullptr, 1024, K, 1.f,
                 by * 128, bx * 128, As, Bs, nullptr, 1 << 30);
  else
    gemm_body<2>(A1, Bt1, C1, nullptr, nullptr, nullptr, 2048, K, 1.f,
                 by * 128, (bx - 8) * 128, As, Bs, Vt, 1024);
}

// ---------------------------------------------------------------------------
// 64x128 GEMM for small-N shapes, 512 threads / 8 waves (2 Mx4 N), each wave
// 32x32 output, XOR-swizzled LDS. grid (N/128, M/64) = 512 blocks.
template <int EPI>
__global__ __launch_bounds__(512) void gemm64_k(
    const bf16* __restrict__ A, const bf16* __restrict__ Bt,
    bf16* __restrict__ Cb, float* __restrict__ Cf,
    const float* __restrict__ bias, const float* __restrict__ resid,
    int N, int K, float mul) {
  __shared__ __align__(16) bf16 As[64 * 64];
  __shared__ __align__(16) bf16 Bs[128 * 64];
  const int tid = threadIdx.x;
  const int l = tid & 63, w = tid >> 6;   // 8 waves
  const int l15 = l & 15, g4 = l >> 4;
  const int wr = w >> 2, wc = w & 3;      // 2 (M) x 4 (N)
  int swz = xcd_swz(blockIdx.y * gridDim.x + blockIdx.x, gridDim.x * gridDim.y);
  const int m0 = (swz / gridDim.x) * 64, n0 = (swz % gridDim.x) * 128;
  f32x4 acc[2][2] = {};
  const int crow = tid >> 3, sj = tid & 7;  // crow 0..63
  const int jeA = ((sj ^ (crow & 7)) << 3);
  for (int k0 = 0; k0 < K; k0 += 64) {
    gload_lds16(A + (size_t)(m0 + crow) * K + (k0 + jeA), (char*)As + tid * 16);
#pragma unroll
    for (int i = 0; i < 2; ++i) {
      int row = i * 64 + crow;
      int je = ((sj ^ (row & 7)) << 3);
      gload_lds16(Bt + (size_t)(n0 + row) * K + (k0 + je), (char*)Bs + (i * 512 + tid) * 16);
    }
    __syncthreads();
#pragma unroll
    for (int kk = 0; kk < 2; ++kk) {
      bf16x8 af[2], bfr[2];
#pragma unroll
      for (int x = 0; x < 2; ++x) {
        af[x]  = *(const bf16x8*)&As[SWZE(wr * 32 + x * 16 + l15, kk * 4 + g4)];
        bfr[x] = *(const bf16x8*)&Bs[SWZE(wc * 32 + x * 16 + l15, kk * 4 + g4)];
      }
      __builtin_amdgcn_s_setprio(1);
#pragma unroll
      for (int mf = 0; mf < 2; ++mf)
#pragma unroll
        for (int nf = 0; nf < 2; ++nf)
          acc[mf][nf] = MFMA(af[mf], bfr[nf], acc[mf][nf]);
      __builtin_amdgcn_s_setprio(0);
    }
    __syncthreads();
  }
#pragma unroll
  for (int mf = 0; mf < 2; ++mf)
#pragma unroll
    for (int nf = 0; nf < 2; ++nf)
#pragma unroll
      for (int r = 0; r < 4; ++r) {
        int row = m0 + wr * 32 + mf * 16 + g4 * 4 + r;
        int col = n0 + wc * 32 + nf * 16 + l15;
        size_t idx = (size_t)row * N + col;
        float v = acc[mf][nf][r];
        if (EPI == 0) {
          Cb[idx] = (bf16)v;
        } else {
          v = mul * fmaxf(v + bias[col], 0.f);
          if (resid) v += resid[idx];
          Cf[idx] = v;
        }
      }
}

// ---------------------------------------------------------------------------
// Flash attention, 128 q-rows/block (8 waves, 512 thr), 32KB LDS, 2-deep
// staging. Waves (qh in 4, kh in 2) = 32q x 32k. No max tracking (|s|<1);
// V^T k-permuted so PV A-frag is pure per-lane repack; row-sum via ones-MFMA;
// kh-reduction via LDS scratch.
// MODE 0: non-causal, direct output (grid 16x32, XCD-swizzled).
// MODE 1: causal K-SPLIT (flash-decoding): grid 1024 = (half, bh, qt); each
//   block does qt+1 chunks [half*(qt+1)..); max block length 16 chunks (was
//   32 -> causal makespan halves; all 1024 blocks resident at 4/CU). Writes
//   UNNORMALIZED partial O (bf16) + l (f32); combine_k sums and normalizes
//   (exact: softmax is max-free, partials combine by pure addition).
template <int MODE>
__global__ __launch_bounds__(512) void attn_k(
    const bf16* __restrict__ Q, int ldq, size_t sBq,
    const bf16* __restrict__ Kp, int ldk, size_t sBk,
    const bf16* __restrict__ Vt,
    bf16* __restrict__ O, int ldo, size_t sBo,
    int Sk, bf16* __restrict__ Opart, float* __restrict__ Lpart) {
  __shared__ __align__(16) char smem[32768];   // Ks[2][8KB] | Vs[2][8KB]; scratch reuse
  bf16* const KsBase = (bf16*)smem;
  bf16* const VsBase = (bf16*)(smem + 16384);
  const int tid = threadIdx.x;
  const int l = tid & 63, w = tid >> 6;   // 8 waves
  const int l15 = l & 15, g4 = l >> 4;
  const int qh = w >> 1, kh = w & 1;      // 4 q-quarters x 2 k-halves
  const int orig = blockIdx.y * gridDim.x + blockIdx.x;
  int qt, bh, half = 0, rest = 0;
  if (MODE == 1) {
    half = orig >> 9; rest = orig & 511;
    bh = rest >> 4; qt = rest & 15;
  } else {
    const int swz = xcd_swz(orig, gridDim.x * gridDim.y);
    qt = swz % gridDim.x;
    bh = swz / gridDim.x;
  }
  const int b = bh >> 4, h = bh & 15;
  const int nT = Sk >> 6;
  const int nCh = (MODE == 1) ? (qt + 1) : nT;       // chunks this block
  const int chStart = (MODE == 1) ? half * (qt + 1) : 0;
  const int q0b = qt * 128;
  const int qw = q0b + qh * 32;           // wave's q-base
  const bf16* Qb = Q + (size_t)b * sBq + h * 64;
  const bf16* Kb = Kp + (size_t)b * sBk + h * 64;
  const bf16* Vb = Vt + ((size_t)bh * 64) * Sk;
  bf16* Ob = O + (size_t)b * sBo + h * 64;
  const float sc2 = rsqrtf((float)Sk) * 1.442695040888963f;  // 1/sqrt(Sk)*log2(e)

  // Q rows for this wave (32 rows), pre-scaled
  bf16x8 qf[2][2];
#pragma unroll
  for (int qg = 0; qg < 2; ++qg)
#pragma unroll
    for (int kk = 0; kk < 2; ++kk) {
      bf16x8 t8 = *(const bf16x8*)(Qb + (size_t)(qw + qg * 16 + l15) * ldq + kk * 32 + g4 * 8);
#pragma unroll
      for (int j = 0; j < 8; ++j) t8[j] = (bf16)((float)t8[j] * sc2);
      qf[qg][kk] = t8;
    }

  bf16x8 onesb;
#pragma unroll
  for (int j = 0; j < 8; ++j) onesb[j] = (bf16)1.0f;

  // o[qg][nf2]: partial O for q = qw+qg*16+g4*4+r, d = nf2*16+l15 (k-half kh)
  f32x4 o[2][4] = {};
  f32x4 ol[2] = {};

  // 512 threads stage 16KB: 1 K-load + 1 V-load per thread per chunk.
  const int srow = tid >> 3, sj = tid & 7;   // srow 0..63
  const int je = ((sj ^ (srow & 7)) << 3);
  auto stage = [&](int ch, int bufi) {
    gload_lds16(Kb + (size_t)(ch * 64 + srow) * ldk + je,
                (char*)(KsBase + bufi * 4096) + tid * 16);
    gload_lds16(Vb + (size_t)srow * Sk + ch * 64 + je,
                (char*)(VsBase + bufi * 4096) + tid * 16);
  };

  stage(chStart, 0);
  waitvm0();
  __builtin_amdgcn_s_barrier();

  int cur = 0;

  for (int i = 0; i < nCh; ++i) {
    if (i + 1 < nCh) stage(chStart + i + 1, cur ^ 1);

    const int gch = chStart + i;
    const int k0 = gch * 64;
    const bf16* ks = KsBase + cur * 4096;
    const bf16* vs = VsBase + cur * 4096;

    // S^T[k = kh*32+ksub*16+g4*4+r][q(qg) = l15] = mfma(A=K-half, B=Q^T)
    f32x4 s[2][2] = {};
    __builtin_amdgcn_s_setprio(1);
#pragma unroll
    for (int ksub = 0; ksub < 2; ++ksub)
#pragma unroll
      for (int kk = 0; kk < 2; ++kk) {
        bf16x8 kf = *(const bf16x8*)&ks[SWZE(kh * 32 + ksub * 16 + l15, kk * 4 + g4)];
        s[ksub][0] = MFMA(kf, qf[0][kk], s[ksub][0]);
        s[ksub][1] = MFMA(kf, qf[1][kk], s[ksub][1]);
      }
    __builtin_amdgcn_s_setprio(0);

    // causal mask needed only when chunk straddles the diagonal band
    bool needMask = (MODE == 1) ? (gch >= 2 * qt) : false;
    if (needMask) {
#pragma unroll
      for (int ksub = 0; ksub < 2; ++ksub)
#pragma unroll
        for (int qg = 0; qg < 2; ++qg)
#pragma unroll
          for (int r = 0; r < 4; ++r)
            if ((k0 + kh * 32 + ksub * 16 + g4 * 4 + r) > (qw + qg * 16 + l15))
              s[ksub][qg][r] = -3e38f;
    }

    // P = exp2(s) directly (masked -> 0)
#pragma unroll
    for (int ksub = 0; ksub < 2; ++ksub)
#pragma unroll
      for (int qg = 0; qg < 2; ++qg) {
        s[ksub][qg][0] = expq(s[ksub][qg][0]);
        s[ksub][qg][1] = expq(s[ksub][qg][1]);
        s[ksub][qg][2] = expq(s[ksub][qg][2]);
        s[ksub][qg][3] = expq(s[ksub][qg][3]);
      }

    // V^T fragments for this k-half (shared by both q-groups): 4 b128 reads
    bf16x8 vf[4];
#pragma unroll
    for (int nf2 = 0; nf2 < 4; ++nf2)
      vf[nf2] = *(const bf16x8*)&vs[SWZE(nf2 * 16 + l15, kh * 4 + g4)];

    __builtin_amdgcn_s_setprio(1);
#pragma unroll
    for (int qg = 0; qg < 2; ++qg) {
      u32x4 td;
      td[0] = cvtpk_bf16(s[0][qg][0], s[0][qg][1]);
      td[1] = cvtpk_bf16(s[0][qg][2], s[0][qg][3]);
      td[2] = cvtpk_bf16(s[1][qg][0], s[1][qg][1]);
      td[3] = cvtpk_bf16(s[1][qg][2], s[1][qg][3]);
      bf16x8 pa = __builtin_bit_cast(bf16x8, td);
#pragma unroll
      for (int nf2 = 0; nf2 < 4; ++nf2)
        o[qg][nf2] = MFMA(pa, vf[nf2], o[qg][nf2]);
      ol[qg] = MFMA(pa, onesb, ol[qg]);
    }
    __builtin_amdgcn_s_setprio(0);

    waitvm0();
    __builtin_amdgcn_s_barrier();
    cur ^= 1;
  }

  // Cross-wave reduction over kh (partner waves share qh), 2 phases (one per
  // qg) through LDS scratch (stride 21 floats per lane, conflict-light).
  {
    float* sc = (float*)smem;
    float* my = sc + (size_t)(qh * 64 + l) * 21;
#pragma unroll
    for (int qg = 0; qg < 2; ++qg) {
      __syncthreads();
      if (kh == 1) {
#pragma unroll
        for (int nf2 = 0; nf2 < 4; ++nf2)
#pragma unroll
          for (int r = 0; r < 4; ++r) my[nf2 * 4 + r] = o[qg][nf2][r];
#pragma unroll
        for (int r = 0; r < 4; ++r) my[16 + r] = ol[qg][r];
      }
      __syncthreads();
      if (kh == 0) {
        if (MODE == 1) {
          // write UNNORMALIZED partial O (bf16) + l (f32)
          bf16* op = Opart + (size_t)orig * 8192;
          float* lp = Lpart + (size_t)orig * 128;
#pragma unroll
          for (int nf2 = 0; nf2 < 4; ++nf2)
#pragma unroll
            for (int r = 0; r < 4; ++r) {
              float v = o[qg][nf2][r] + my[nf2 * 4 + r];
              op[(qh * 32 + qg * 16 + g4 * 4 + r) * 64 + nf2 * 16 + l15] = (bf16)v;
            }
          if (l15 == 0) {
#pragma unroll
            for (int r = 0; r < 4; ++r)
              lp[qh * 32 + qg * 16 + g4 * 4 + r] = ol[qg][r] + my[16 + r];
          }
        } else {
          float inv[4];
#pragma unroll
          for (int r = 0; r < 4; ++r) inv[r] = rcpq(ol[qg][r] + my[16 + r]);
#pragma unroll
          for (int nf2 = 0; nf2 < 4; ++nf2)
#pragma unroll
            for (int r = 0; r < 4; ++r) {
              float v = (o[qg][nf2][r] + my[nf2 * 4 + r]) * inv[r];
              Ob[(size_t)(qw + qg * 16 + g4 * 4 + r) * ldo + nf2 * 16 + l15] = (bf16)v;
            }
        }
      }
    }
  }
}

// ---------------------------------------------------------------------------
// combine_k: merge the two causal k-split partials: O = (O0+O1)/(l0+l1).
// 512 blocks = (bh, qt); partial index c and 512+c. Output into ATT
// (row b*2048 + qt*128 + q, col h*64 + d, ld 1024).
__global__ __launch_bounds__(256) void combine_k(
    const bf16* __restrict__ Opart, const float* __restrict__ Lpart,
    bf16* __restrict__ ATT) {
  const int c = blockIdx.x;
  const int qt = c & 15, bh = c >> 4, b = bh >> 4, h = bh & 15;
  const bf16* o0 = Opart + (size_t)c * 8192;
  const bf16* o1 = Opart + (size_t)(512 + c) * 8192;
  const float* l0 = Lpart + (size_t)c * 128;
  const float* l1 = Lpart + (size_t)(512 + c) * 128;
  const int t = threadIdx.x;
#pragma unroll
  for (int e = 0; e < 8; ++e) {
    int idx = e * 1024 + t * 4;            // 4 contiguous elems per thread
    int q = idx >> 6, d = idx & 63;
    float inv = rcpq(l0[q] + l1[q]);
    bf16x4 a = *(const bf16x4*)(o0 + idx);
    bf16x4 bb = *(const bf16x4*)(o1 + idx);
    bf16x4 r;
#pragma unroll
    for (int j = 0; j < 4; ++j) r[j] = (bf16)(((float)a[j] + (float)bb[j]) * inv);
    *(bf16x4*)(ATT + ((size_t)(b * 2048 + qt * 128 + q) * 1024) + h * 64 + d) = r;
  }
}

// ---------------------------------------------------------------------------
__global__ __launch_bounds__(256) void ln_k(const float* __restrict__ X,
                                            const float* __restrict__ g,
                                            const float* __restrict__ bta,
                                            bf16* __restrict__ outb,
                                            float* __restrict__ outf) {
  const int tid = threadIdx.x;
  const size_t row = blockIdx.x;
  const float* x = X + row * 1024;
  float4 v = *(const float4*)(x + tid * 4);
  float sum = v.x + v.y + v.z + v.w;
  float sq = v.x * v.x + v.y * v.y + v.z * v.z + v.w * v.w;
#pragma unroll
  for (int m = 1; m < 64; m <<= 1) {
    sum += __shfl_xor(sum, m);
    sq += __shfl_xor(sq, m);
  }
  __shared__ float s1[4], s2[4];
  int w = tid >> 6;
  if ((tid & 63) == 0) { s1[w] = sum; s2[w] = sq; }
  __syncthreads();
  sum = s1[0] + s1[1] + s1[2] + s1[3];
  sq = s2[0] + s2[1] + s2[2] + s2[3];
  float mean = sum * (1.f / 1024.f);
  float var = sq * (1.f / 1024.f) - mean * mean;
  float inv = rsqrtf(var + 1e-6f);
  float4 gv = *(const float4*)(g + tid * 4);
  float4 bv = *(const float4*)(bta + tid * 4);
  float y0 = (v.x - mean) * inv * gv.x + bv.x;
  float y1 = (v.y - mean) * inv * gv.y + bv.y;
  float y2 = (v.z - mean) * inv * gv.z + bv.z;
  float y3 = (v.w - mean) * inv * gv.w + bv.w;
  if (outb) {
    bf16x4 ob;
    ob[0] = (bf16)y0; ob[1] = (bf16)y1; ob[2] = (bf16)y2; ob[3] = (bf16)y3;
    *(bf16x4*)(outb + row * 1024 + tid * 4) = ob;
  }
  if (outf) {
    float4 of;
    of.x = y0; of.y = y1; of.z = y2; of.w = y3;
    *(float4*)(outf + row * 1024 + tid * 4) = of;
  }
}

// ---------------------------------------------------------------------------
extern "C" void kernel_launch(void* const* d_in, const int* in_sizes, int n_in,
                              void* d_out, int out_size, void* d_ws, size_t ws_size,
                              hipStream_t stream) {
  (void)in_sizes; (void)n_in; (void)out_size; (void)ws_size;
  const float* inp = (const float*)d_in[0];
  const float* ctx = (const float*)d_in[1];
  const float* Wk1 = (const float*)d_in[2];
  const float* Wv1 = (const float*)d_in[3];
  const float* Wq1 = (const float*)d_in[4];
  const float* Wo1 = (const float*)d_in[5];
  const float* bo1 = (const float*)d_in[6];
  const float* Wk2 = (const float*)d_in[7];
  const float* Wv2 = (const float*)d_in[8];
  const float* Wq2 = (const float*)d_in[9];
  const float* Wo2 = (const float*)d_in[10];
  const float* bo2 = (const float*)d_in[11];
  const float* Wf = (const float*)d_in[12];
  const float* bfp = (const float*)d_in[13];
  const float* g1 = (const float*)d_in[14];
  const float* b1 = (const float*)d_in[15];
  const float* g2 = (const float*)d_in[16];
  const float* b2 = (const float*)d_in[17];
  const float* g3 = (const float*)d_in[18];
  const float* b3 = (const float*)d_in[19];
  float* out = (float*)d_out;

  char* ws = (char*)d_ws;
  size_t off = 0;
  auto alloc = [&](size_t bytes) {
    char* p = ws + off;
    off += (bytes + 255) & ~(size_t)255;
    return p;
  };
  bf16* XB = (bf16*)alloc(4096ULL * 1024 * 2);       // inputs bf16; reused as AB
  bf16* CB = (bf16*)alloc(4096ULL * 1024 * 2);       // context bf16; reused as CBf
  bf16* WQKV1 = (bf16*)alloc(3072ULL * 1024 * 2);
  bf16* WO1 = (bf16*)alloc(1024ULL * 1024 * 2);
  bf16* WQ2 = (bf16*)alloc(1024ULL * 1024 * 2);
  bf16* WKV2 = (bf16*)alloc(2048ULL * 1024 * 2);
  bf16* WO2 = (bf16*)alloc(1024ULL * 1024 * 2);
  bf16* WFt = (bf16*)alloc(1024ULL * 1024 * 2);
  bf16* QKV1 = (bf16*)alloc(4096ULL * 3072 * 2);     // later: Q2 (first 8MB) + KV2 (next 16MB)
  bf16* V1T = (bf16*)alloc(32ULL * 64 * 2048 * 2);   // reused as V2T
  bf16* ATT1 = (bf16*)alloc(4096ULL * 1024 * 2);     // reused as ATT2
  float* T1 = (float*)alloc(4096ULL * 1024 * 4);     // reused as T2, T3
  float* CF = (float*)alloc(4096ULL * 1024 * 4);
  bf16* OPart = (bf16*)alloc(1024ULL * 8192 * 2);    // causal k-split partial O
  float* LPart = (float*)alloc(1024ULL * 128 * 4);   // causal k-split partial l

  bf16* AB = XB;
  bf16* CBf = CB;
  bf16* Q2 = QKV1;
  bf16* KV2 = QKV1 + 4096ULL * 1024;
  bf16* V2T = V1T;
  bf16* ATT2 = ATT1;
  float* T2 = T1;
  float* T3 = T1;

  dim3 b256(256);
  dim3 b512(512);

  // fused convert + all weight packs (one launch)
  prep_k<<<10496, b256, 0, stream>>>(inp, ctx, XB, CB,
                                     Wq1, Wk1, Wv1, Wq2, Wk2, Wv2,
                                     WQKV1, WQ2, WKV2,
                                     Wo1, Wo2, Wf, WO1, WO2, WFt);

  // ---- layer 1: masked self-attention (k-split + combine) ----
  gemm_qkv_k<<<dim3(24, 32), b256, 0, stream>>>(XB, WQKV1, QKV1, V1T, 3072, 1024, 2048);
  attn_k<1><<<dim3(32, 32), b512, 0, stream>>>(QKV1, 3072, (size_t)2048 * 3072,
                                               QKV1 + 1024, 3072, (size_t)2048 * 3072,
                                               V1T, ATT1, 1024, (size_t)2048 * 1024, 2048,
                                               OPart, LPart);
  combine_k<<<512, b256, 0, stream>>>(OPart, LPart, ATT1);
  gemm64_k<1><<<dim3(8, 64), b512, 0, stream>>>(ATT1, WO1, nullptr, T1, bo1, inp,
                                                1024, 1024, 1.f);
  ln_k<<<4096, b256, 0, stream>>>(T1, g1, b1, AB, nullptr);

  // ---- layer 2: cross-attention (Q from a, K/V from context), merged GEMM ----
  gemm_bt2_k<<<dim3(24, 32), b256, 0, stream>>>(AB, WQ2, Q2, CB, WKV2, KV2, V2T, 1024);
  attn_k<0><<<dim3(16, 32), b512, 0, stream>>>(Q2, 1024, (size_t)2048 * 1024,
                                               KV2, 2048, (size_t)2048 * 2048,
                                               V2T, ATT2, 1024, (size_t)2048 * 1024, 2048,
                                               nullptr, nullptr);
  gemm64_k<1><<<dim3(8, 64), b512, 0, stream>>>(ATT2, WO2, nullptr, T2, bo2, nullptr,
                                                1024, 1024, 2.f);
  ln_k<<<4096, b256, 0, stream>>>(T2, g2, b2, CBf, CF);

  // ---- FFN + final LN ----
  gemm64_k<1><<<dim3(8, 64), b512, 0, stream>>>(CBf, WFt, nullptr, T3, bfp, CF,
                                                1024, 1024, 1.f);
  ln_k<<<4096, b256, 0, stream>>>(T3, g3, b3, nullptr, out);
}

// Round 19
// 226.778 us; speedup vs baseline: 1.0295x; 1.0295x over previous
//
#include <hip/hip_runtime.h>
#include <stdint.h>
#include <stddef.h>

typedef __bf16 bf16;
typedef __bf16 bf16x8 __attribute__((ext_vector_type(8)));
typedef __bf16 bf16x4 __attribute__((ext_vector_type(4)));
typedef float  f32x4  __attribute__((ext_vector_type(4)));
typedef uint32_t u32x4 __attribute__((ext_vector_type(4)));

#define MFMA(a, b, c) __builtin_amdgcn_mfma_f32_16x16x32_bf16((a), (b), (c), 0, 0, 0)
// element offset of (row, 16B-chunk) in a swizzled [*][64] bf16 tile
#define SWZE(row, chunk) (((row) << 6) + ((((chunk) ^ ((row) & 7))) << 3))

static __device__ __forceinline__ void gload_lds16(const void* g, void* l) {
  __builtin_amdgcn_global_load_lds((const __attribute__((address_space(1))) void*)g,
                                   (__attribute__((address_space(3))) void*)l,
                                   16, 0, 0);
}
static __device__ __forceinline__ void waitvm0() {
  asm volatile("s_waitcnt vmcnt(0)" ::: "memory");
}
static __device__ __forceinline__ float expq(float x) {  // raw v_exp_f32 (2^x)
  float r;
  asm("v_exp_f32 %0, %1" : "=v"(r) : "v"(x));
  return r;
}
static __device__ __forceinline__ float rcpq(float x) {
  float r;
  asm("v_rcp_f32 %0, %1" : "=v"(r) : "v"(x));
  return r;
}
static __device__ __forceinline__ uint32_t cvtpk_bf16(float lo, float hi) {
  uint32_t r;
  asm("v_cvt_pk_bf16_f32 %0, %1, %2" : "=v"(r) : "v"(lo), "v"(hi));
  return r;
}
// bijective XCD swizzle (requires nwg % 8 == 0)
static __device__ __forceinline__ int xcd_swz(int orig, int nwg) {
  return (orig & 7) * (nwg >> 3) + (orig >> 3);
}
// V^T k-permutation within each 32-block: staged slot t holds V row
// k_phys(t) = t2<<4 | t4<<3 | t3<<2 | t1<<1 | t0. Inverse (store side):
// row s goes to slot (s&~31) | s3<<4 | s2<<3 | s4<<2 | (s&3)
static __device__ __forceinline__ int vperm_store(int s) {
  return (s & ~31) | (((s >> 3) & 1) << 4) | (((s >> 2) & 1) << 3) |
         (((s >> 4) & 1) << 2) | (s & 3);
}

// ---------------------------------------------------------------------------
// prep_k: fused input-convert + all weight packing (one launch).
__global__ __launch_bounds__(256) void prep_k(
    const float* __restrict__ inp, const float* __restrict__ ctx,
    bf16* __restrict__ XB, bf16* __restrict__ CB,
    const float* __restrict__ Wq1, const float* __restrict__ Wk1,
    const float* __restrict__ Wv1, const float* __restrict__ Wq2,
    const float* __restrict__ Wk2, const float* __restrict__ Wv2,
    bf16* __restrict__ WQKV1, bf16* __restrict__ WQ2, bf16* __restrict__ WKV2,
    const float* __restrict__ Wo1, const float* __restrict__ Wo2,
    const float* __restrict__ Wf,
    bf16* __restrict__ WO1, bf16* __restrict__ WO2, bf16* __restrict__ WFt) {
  const int tid = threadIdx.x;
  int bx = blockIdx.x;
  if (bx < 8192) {
    const float* s = bx < 4096 ? inp : ctx;
    bf16* d = bx < 4096 ? XB : CB;
    size_t idx = (size_t)(bx & 4095) * 256 + tid;
    float4 v = *(const float4*)(s + idx * 4);
    bf16x4 o;
    o[0] = (bf16)v.x; o[1] = (bf16)v.y; o[2] = (bf16)v.z; o[3] = (bf16)v.w;
    *(bf16x4*)(d + idx * 4) = o;
    return;
  }
  bx -= 8192;
  __shared__ float T[64][65];
  if (bx < 1536) {
    const int wi = bx >> 8, sub = bx & 255;
    const float* src = (wi == 0) ? Wq1 : (wi == 1) ? Wk1 : (wi == 2) ? Wv1
                     : (wi == 3) ? Wq2 : (wi == 4) ? Wk2 : Wv2;
    bf16* dst = (wi == 0) ? WQKV1 : (wi == 1) ? WQKV1 + 1048576
              : (wi == 2) ? WQKV1 + 2097152 : (wi == 3) ? WQ2
              : (wi == 4) ? WKV2 : WKV2 + 1048576;
    const int e0 = (sub & 15) * 64, h = sub >> 4;
    const int er = tid >> 4, dof = (tid & 15) * 4;
#pragma unroll
    for (int i = 0; i < 4; ++i) {
      int e = i * 16 + er;
      float4 v = *(const float4*)(src + ((size_t)h * 1024 + e0 + e) * 64 + dof);
      T[e][dof] = v.x; T[e][dof + 1] = v.y; T[e][dof + 2] = v.z; T[e][dof + 3] = v.w;
    }
    __syncthreads();
    const int dr = tid >> 3, eo = (tid & 7) * 8;
#pragma unroll
    for (int i = 0; i < 2; ++i) {
      int d = i * 32 + dr;
      bf16x8 ov;
#pragma unroll
      for (int j = 0; j < 8; ++j) ov[j] = (bf16)T[eo + j][d];
      *(bf16x8*)(dst + ((size_t)h * 64 + d) * 1024 + e0 + eo) = ov;
    }
    return;
  }
  bx -= 1536;
  {
    const int wi = bx >> 8, sub = bx & 255;
    const float* src = (wi == 0) ? Wo1 : (wi == 1) ? Wo2 : Wf;
    bf16* dst = (wi == 0) ? WO1 : (wi == 1) ? WO2 : WFt;
    const int k0 = (sub & 15) * 64, n0 = (sub >> 4) * 64;
    const int kr = tid >> 4, no = (tid & 15) * 4;
#pragma unroll
    for (int i = 0; i < 4; ++i) {
      int k = i * 16 + kr;
      float4 v = *(const float4*)(src + (size_t)(k0 + k) * 1024 + n0 + no);
      T[k][no] = v.x; T[k][no + 1] = v.y; T[k][no + 2] = v.z; T[k][no + 3] = v.w;
    }
    __syncthreads();
    const int nr = tid >> 3, ko = (tid & 7) * 8;
#pragma unroll
    for (int i = 0; i < 2; ++i) {
      int n = i * 32 + nr;
      bf16x8 ov;
#pragma unroll
      for (int j = 0; j < 8; ++j) ov[j] = (bf16)T[ko + j][n];
      *(bf16x8*)(dst + (size_t)(n0 + n) * 1024 + k0 + ko) = ov;
    }
  }
}

// ---------------------------------------------------------------------------
// 128x128 GEMM body, XOR-swizzled LDS tiles (conflict-free ds_read_b128).
template <int EPI>
static __device__ __forceinline__ void gemm_body(
    const bf16* __restrict__ A, const bf16* __restrict__ Bt,
    bf16* __restrict__ Cb, float* __restrict__ Cf,
    const float* __restrict__ bias, const float* __restrict__ resid,
    int N, int K, float mul, int m0, int n0, bf16* As, bf16* Bs,
    bf16* __restrict__ Vt, int colV) {
  const int tid = threadIdx.x;
  const int l = tid & 63, w = tid >> 6;
  const int l15 = l & 15, g4 = l >> 4;
  const int wr = w >> 1, wc = w & 1;
  f32x4 acc[4][4] = {};
  const int crow = tid >> 3, sj = tid & 7;
  for (int k0 = 0; k0 < K; k0 += 64) {
#pragma unroll
    for (int i = 0; i < 4; ++i) {
      int row = i * 32 + crow;
      int je = ((sj ^ (row & 7)) << 3);   // pre-swizzled source chunk
      gload_lds16(A + (size_t)(m0 + row) * K + (k0 + je), (char*)As + (i * 256 + tid) * 16);
      gload_lds16(Bt + (size_t)(n0 + row) * K + (k0 + je), (char*)Bs + (i * 256 + tid) * 16);
    }
    __syncthreads();
#pragma unroll
    for (int kk = 0; kk < 2; ++kk) {
      bf16x8 af[4], bfr[4];
#pragma unroll
      for (int x = 0; x < 4; ++x) {
        af[x]  = *(const bf16x8*)&As[SWZE(wr * 64 + x * 16 + l15, kk * 4 + g4)];
        bfr[x] = *(const bf16x8*)&Bs[SWZE(wc * 64 + x * 16 + l15, kk * 4 + g4)];
      }
      __builtin_amdgcn_s_setprio(1);
#pragma unroll
      for (int mf = 0; mf < 4; ++mf)
#pragma unroll
        for (int nf = 0; nf < 4; ++nf)
          acc[mf][nf] = MFMA(af[mf], bfr[nf], acc[mf][nf]);
      __builtin_amdgcn_s_setprio(0);
    }
    __syncthreads();
  }
  if (EPI == 2 && n0 >= colV) {
#pragma unroll
    for (int mf = 0; mf < 4; ++mf)
#pragma unroll
      for (int nf = 0; nf < 4; ++nf) {
        int colrel = n0 + wc * 64 + nf * 16 + l15 - colV;
        int h = colrel >> 6, d = colrel & 63;
        int row = m0 + wr * 64 + mf * 16 + g4 * 4;
        int b = row >> 11, s = row & 2047;
        bf16x4 pv;
#pragma unroll
        for (int r = 0; r < 4; ++r) pv[r] = (bf16)acc[mf][nf][r];
        *(bf16x4*)(Vt + (((size_t)(b * 16 + h) * 64 + d) * 2048 + vperm_store(s))) = pv;
      }
    return;
  }
#pragma unroll
  for (int mf = 0; mf < 4; ++mf)
#pragma unroll
    for (int nf = 0; nf < 4; ++nf)
#pragma unroll
      for (int r = 0; r < 4; ++r) {
        int row = m0 + wr * 64 + mf * 16 + g4 * 4 + r;
        int col = n0 + wc * 64 + nf * 16 + l15;
        size_t idx = (size_t)row * N + col;
        float v = acc[mf][nf][r];
        if (EPI == 1) {
          v = mul * fmaxf(v + bias[col], 0.f);
          if (resid) v += resid[idx];
          Cf[idx] = v;
        } else {
          Cb[idx] = (bf16)v;
        }
      }
}

// QKV projection GEMM (N=3072), V block-columns written transposed to Vt
__global__ __launch_bounds__(256) void gemm_qkv_k(
    const bf16* __restrict__ A, const bf16* __restrict__ Bt,
    bf16* __restrict__ Cb, bf16* __restrict__ Vt, int N, int K, int colV) {
  __shared__ __align__(16) bf16 As[128 * 64];
  __shared__ __align__(16) bf16 Bs[128 * 64];
  int swz = xcd_swz(blockIdx.y * gridDim.x + blockIdx.x, gridDim.x * gridDim.y);
  int bx = swz % gridDim.x, by = swz / gridDim.x;
  gemm_body<2>(A, Bt, Cb, nullptr, nullptr, nullptr, N, K, 1.f,
               by * 128, bx * 128, As, Bs, Vt, colV);
}

// Merged dispatch for layer 2: x<8 -> Q2 (N=1024), else KV2 (N=2048, V->V2T)
__global__ __launch_bounds__(256) void gemm_bt2_k(
    const bf16* __restrict__ A0, const bf16* __restrict__ Bt0, bf16* __restrict__ C0,
    const bf16* __restrict__ A1, const bf16* __restrict__ Bt1, bf16* __restrict__ C1,
    bf16* __restrict__ Vt, int K) {
  __shared__ __align__(16) bf16 As[128 * 64];
  __shared__ __align__(16) bf16 Bs[128 * 64];
  int swz = xcd_swz(blockIdx.y * gridDim.x + blockIdx.x, gridDim.x * gridDim.y);
  int bx = swz % gridDim.x, by = swz / gridDim.x;
  if (bx < 8)
    gemm_body<0>(A0, Bt0, C0, nullptr, nullptr, nullptr, 1024, K, 1.f,
                 by * 128, bx * 128, As, Bs, nullptr, 1 << 30);
  else
    gemm_body<2>(A1, Bt1, C1, nullptr, nullptr, nullptr, 2048, K, 1.f,
                 by * 128, (bx - 8) * 128, As, Bs, Vt, 1024);
}

// ---------------------------------------------------------------------------
// 64x128 GEMM for small-N shapes, 512 threads / 8 waves (2 Mx4 N), each wave
// 32x32 output, XOR-swizzled LDS. grid (N/128, M/64) = 512 blocks.
template <int EPI>
__global__ __launch_bounds__(512) void gemm64_k(
    const bf16* __restrict__ A, const bf16* __restrict__ Bt,
    bf16* __restrict__ Cb, float* __restrict__ Cf,
    const float* __restrict__ bias, const float* __restrict__ resid,
    int N, int K, float mul) {
  __shared__ __align__(16) bf16 As[64 * 64];
  __shared__ __align__(16) bf16 Bs[128 * 64];
  const int tid = threadIdx.x;
  const int l = tid & 63, w = tid >> 6;   // 8 waves
  const int l15 = l & 15, g4 = l >> 4;
  const int wr = w >> 2, wc = w & 3;      // 2 (M) x 4 (N)
  int swz = xcd_swz(blockIdx.y * gridDim.x + blockIdx.x, gridDim.x * gridDim.y);
  const int m0 = (swz / gridDim.x) * 64, n0 = (swz % gridDim.x) * 128;
  f32x4 acc[2][2] = {};
  const int crow = tid >> 3, sj = tid & 7;  // crow 0..63
  const int jeA = ((sj ^ (crow & 7)) << 3);
  for (int k0 = 0; k0 < K; k0 += 64) {
    gload_lds16(A + (size_t)(m0 + crow) * K + (k0 + jeA), (char*)As + tid * 16);
#pragma unroll
    for (int i = 0; i < 2; ++i) {
      int row = i * 64 + crow;
      int je = ((sj ^ (row & 7)) << 3);
      gload_lds16(Bt + (size_t)(n0 + row) * K + (k0 + je), (char*)Bs + (i * 512 + tid) * 16);
    }
    __syncthreads();
#pragma unroll
    for (int kk = 0; kk < 2; ++kk) {
      bf16x8 af[2], bfr[2];
#pragma unroll
      for (int x = 0; x < 2; ++x) {
        af[x]  = *(const bf16x8*)&As[SWZE(wr * 32 + x * 16 + l15, kk * 4 + g4)];
        bfr[x] = *(const bf16x8*)&Bs[SWZE(wc * 32 + x * 16 + l15, kk * 4 + g4)];
      }
      __builtin_amdgcn_s_setprio(1);
#pragma unroll
      for (int mf = 0; mf < 2; ++mf)
#pragma unroll
        for (int nf = 0; nf < 2; ++nf)
          acc[mf][nf] = MFMA(af[mf], bfr[nf], acc[mf][nf]);
      __builtin_amdgcn_s_setprio(0);
    }
    __syncthreads();
  }
#pragma unroll
  for (int mf = 0; mf < 2; ++mf)
#pragma unroll
    for (int nf = 0; nf < 2; ++nf)
#pragma unroll
      for (int r = 0; r < 4; ++r) {
        int row = m0 + wr * 32 + mf * 16 + g4 * 4 + r;
        int col = n0 + wc * 32 + nf * 16 + l15;
        size_t idx = (size_t)row * N + col;
        float v = acc[mf][nf][r];
        if (EPI == 0) {
          Cb[idx] = (bf16)v;
        } else {
          v = mul * fmaxf(v + bias[col], 0.f);
          if (resid) v += resid[idx];
          Cf[idx] = v;
        }
      }
}

// ---------------------------------------------------------------------------
// Flash attention, 128 q-rows/block (8 waves, 512 thr), 32KB LDS, 2-deep
// staging. Waves (qh in 4, kh in 2) = 32q x 32k. No max tracking (|s|<1);
// V^T k-permuted so PV A-frag is pure per-lane repack; row-sum via ones-MFMA;
// kh-reduction via LDS scratch.
// MODE 0: non-causal, direct output (grid 16x32, XCD-swizzled).
// MODE 1: causal K-SPLIT (flash-decoding), XCD-LOCAL: blocks sharing a
//   (b,h) K/V stripe all land on XCD = bh&7 (4 bh/XCD x 512KB = 2MB, fits
//   the 4MB per-XCD L2 -> no cross-XCD refetch). Each block does qt+1
//   chunks starting at half*(qt+1); writes UNNORMALIZED partial O (bf16)
//   + l (f32) at logical slot half*512+bh*16+qt; combine_k sums+normalizes.
template <int MODE>
__global__ __launch_bounds__(512) void attn_k(
    const bf16* __restrict__ Q, int ldq, size_t sBq,
    const bf16* __restrict__ Kp, int ldk, size_t sBk,
    const bf16* __restrict__ Vt,
    bf16* __restrict__ O, int ldo, size_t sBo,
    int Sk, bf16* __restrict__ Opart, float* __restrict__ Lpart) {
  __shared__ __align__(16) char smem[32768];   // Ks[2][8KB] | Vs[2][8KB]; scratch reuse
  bf16* const KsBase = (bf16*)smem;
  bf16* const VsBase = (bf16*)(smem + 16384);
  const int tid = threadIdx.x;
  const int l = tid & 63, w = tid >> 6;   // 8 waves
  const int l15 = l & 15, g4 = l >> 4;
  const int qh = w >> 1, kh = w & 1;      // 4 q-quarters x 2 k-halves
  const int orig = blockIdx.y * gridDim.x + blockIdx.x;
  int qt, bh, half = 0, lidx = 0;
  if (MODE == 1) {
    // XCD-local: XCD = orig&7 handles bh in {xcd, xcd+8, xcd+16, xcd+24}
    const int xcd = orig & 7, idx = orig >> 3;
    bh = xcd + 8 * (idx >> 5);
    const int rest = idx & 31;
    half = rest >> 4;
    qt = rest & 15;
    lidx = half * 512 + bh * 16 + qt;     // logical partial slot
  } else {
    const int swz = xcd_swz(orig, gridDim.x * gridDim.y);
    qt = swz % gridDim.x;
    bh = swz / gridDim.x;
  }
  const int b = bh >> 4, h = bh & 15;
  const int nT = Sk >> 6;
  const int nCh = (MODE == 1) ? (qt + 1) : nT;       // chunks this block
  const int chStart = (MODE == 1) ? half * (qt + 1) : 0;
  const int q0b = qt * 128;
  const int qw = q0b + qh * 32;           // wave's q-base
  const bf16* Qb = Q + (size_t)b * sBq + h * 64;
  const bf16* Kb = Kp + (size_t)b * sBk + h * 64;
  const bf16* Vb = Vt + ((size_t)bh * 64) * Sk;
  bf16* Ob = O + (size_t)b * sBo + h * 64;
  const float sc2 = rsqrtf((float)Sk) * 1.442695040888963f;  // 1/sqrt(Sk)*log2(e)

  // Q rows for this wave (32 rows), pre-scaled
  bf16x8 qf[2][2];
#pragma unroll
  for (int qg = 0; qg < 2; ++qg)
#pragma unroll
    for (int kk = 0; kk < 2; ++kk) {
      bf16x8 t8 = *(const bf16x8*)(Qb + (size_t)(qw + qg * 16 + l15) * ldq + kk * 32 + g4 * 8);
#pragma unroll
      for (int j = 0; j < 8; ++j) t8[j] = (bf16)((float)t8[j] * sc2);
      qf[qg][kk] = t8;
    }

  bf16x8 onesb;
#pragma unroll
  for (int j = 0; j < 8; ++j) onesb[j] = (bf16)1.0f;

  // o[qg][nf2]: partial O for q = qw+qg*16+g4*4+r, d = nf2*16+l15 (k-half kh)
  f32x4 o[2][4] = {};
  f32x4 ol[2] = {};

  // 512 threads stage 16KB: 1 K-load + 1 V-load per thread per chunk.
  const int srow = tid >> 3, sj = tid & 7;   // srow 0..63
  const int je = ((sj ^ (srow & 7)) << 3);
  auto stage = [&](int ch, int bufi) {
    gload_lds16(Kb + (size_t)(ch * 64 + srow) * ldk + je,
                (char*)(KsBase + bufi * 4096) + tid * 16);
    gload_lds16(Vb + (size_t)srow * Sk + ch * 64 + je,
                (char*)(VsBase + bufi * 4096) + tid * 16);
  };

  stage(chStart, 0);
  waitvm0();
  __builtin_amdgcn_s_barrier();

  int cur = 0;

  for (int i = 0; i < nCh; ++i) {
    if (i + 1 < nCh) stage(chStart + i + 1, cur ^ 1);

    const int gch = chStart + i;
    const int k0 = gch * 64;
    const bf16* ks = KsBase + cur * 4096;
    const bf16* vs = VsBase + cur * 4096;

    // S^T[k = kh*32+ksub*16+g4*4+r][q(qg) = l15] = mfma(A=K-half, B=Q^T)
    f32x4 s[2][2] = {};
    __builtin_amdgcn_s_setprio(1);
#pragma unroll
    for (int ksub = 0; ksub < 2; ++ksub)
#pragma unroll
      for (int kk = 0; kk < 2; ++kk) {
        bf16x8 kf = *(const bf16x8*)&ks[SWZE(kh * 32 + ksub * 16 + l15, kk * 4 + g4)];
        s[ksub][0] = MFMA(kf, qf[0][kk], s[ksub][0]);
        s[ksub][1] = MFMA(kf, qf[1][kk], s[ksub][1]);
      }
    __builtin_amdgcn_s_setprio(0);

    // causal mask needed only when chunk straddles the diagonal band
    bool needMask = (MODE == 1) ? (gch >= 2 * qt) : false;
    if (needMask) {
#pragma unroll
      for (int ksub = 0; ksub < 2; ++ksub)
#pragma unroll
        for (int qg = 0; qg < 2; ++qg)
#pragma unroll
          for (int r = 0; r < 4; ++r)
            if ((k0 + kh * 32 + ksub * 16 + g4 * 4 + r) > (qw + qg * 16 + l15))
              s[ksub][qg][r] = -3e38f;
    }

    // P = exp2(s) directly (masked -> 0)
#pragma unroll
    for (int ksub = 0; ksub < 2; ++ksub)
#pragma unroll
      for (int qg = 0; qg < 2; ++qg) {
        s[ksub][qg][0] = expq(s[ksub][qg][0]);
        s[ksub][qg][1] = expq(s[ksub][qg][1]);
        s[ksub][qg][2] = expq(s[ksub][qg][2]);
        s[ksub][qg][3] = expq(s[ksub][qg][3]);
      }

    // V^T fragments for this k-half (shared by both q-groups): 4 b128 reads
    bf16x8 vf[4];
#pragma unroll
    for (int nf2 = 0; nf2 < 4; ++nf2)
      vf[nf2] = *(const bf16x8*)&vs[SWZE(nf2 * 16 + l15, kh * 4 + g4)];

    __builtin_amdgcn_s_setprio(1);
#pragma unroll
    for (int qg = 0; qg < 2; ++qg) {
      u32x4 td;
      td[0] = cvtpk_bf16(s[0][qg][0], s[0][qg][1]);
      td[1] = cvtpk_bf16(s[0][qg][2], s[0][qg][3]);
      td[2] = cvtpk_bf16(s[1][qg][0], s[1][qg][1]);
      td[3] = cvtpk_bf16(s[1][qg][2], s[1][qg][3]);
      bf16x8 pa = __builtin_bit_cast(bf16x8, td);
#pragma unroll
      for (int nf2 = 0; nf2 < 4; ++nf2)
        o[qg][nf2] = MFMA(pa, vf[nf2], o[qg][nf2]);
      ol[qg] = MFMA(pa, onesb, ol[qg]);
    }
    __builtin_amdgcn_s_setprio(0);

    waitvm0();
    __builtin_amdgcn_s_barrier();
    cur ^= 1;
  }

  // Cross-wave reduction over kh (partner waves share qh), 2 phases (one per
  // qg) through LDS scratch (stride 21 floats per lane, conflict-light).
  {
    float* sc = (float*)smem;
    float* my = sc + (size_t)(qh * 64 + l) * 21;
#pragma unroll
    for (int qg = 0; qg < 2; ++qg) {
      __syncthreads();
      if (kh == 1) {
#pragma unroll
        for (int nf2 = 0; nf2 < 4; ++nf2)
#pragma unroll
          for (int r = 0; r < 4; ++r) my[nf2 * 4 + r] = o[qg][nf2][r];
#pragma unroll
        for (int r = 0; r < 4; ++r) my[16 + r] = ol[qg][r];
      }
      __syncthreads();
      if (kh == 0) {
        if (MODE == 1) {
          // write UNNORMALIZED partial O (bf16) + l (f32)
          bf16* op = Opart + (size_t)lidx * 8192;
          float* lp = Lpart + (size_t)lidx * 128;
#pragma unroll
          for (int nf2 = 0; nf2 < 4; ++nf2)
#pragma unroll
            for (int r = 0; r < 4; ++r) {
              float v = o[qg][nf2][r] + my[nf2 * 4 + r];
              op[(qh * 32 + qg * 16 + g4 * 4 + r) * 64 + nf2 * 16 + l15] = (bf16)v;
            }
          if (l15 == 0) {
#pragma unroll
            for (int r = 0; r < 4; ++r)
              lp[qh * 32 + qg * 16 + g4 * 4 + r] = ol[qg][r] + my[16 + r];
          }
        } else {
          float inv[4];
#pragma unroll
          for (int r = 0; r < 4; ++r) inv[r] = rcpq(ol[qg][r] + my[16 + r]);
#pragma unroll
          for (int nf2 = 0; nf2 < 4; ++nf2)
#pragma unroll
            for (int r = 0; r < 4; ++r) {
              float v = (o[qg][nf2][r] + my[nf2 * 4 + r]) * inv[r];
              Ob[(size_t)(qw + qg * 16 + g4 * 4 + r) * ldo + nf2 * 16 + l15] = (bf16)v;
            }
        }
      }
    }
  }
}

// ---------------------------------------------------------------------------
// combine_k: merge the two causal k-split partials: O = (O0+O1)/(l0+l1).
// 512 blocks = (bh, qt); partial slots c and 512+c. Output into ATT
// (row b*2048 + qt*128 + q, col h*64 + d, ld 1024).
__global__ __launch_bounds__(256) void combine_k(
    const bf16* __restrict__ Opart, const float* __restrict__ Lpart,
    bf16* __restrict__ ATT) {
  const int c = blockIdx.x;
  const int qt = c & 15, bh = c >> 4, b = bh >> 4, h = bh & 15;
  const bf16* o0 = Opart + (size_t)c * 8192;
  const bf16* o1 = Opart + (size_t)(512 + c) * 8192;
  const float* l0 = Lpart + (size_t)c * 128;
  const float* l1 = Lpart + (size_t)(512 + c) * 128;
  const int t = threadIdx.x;
#pragma unroll
  for (int e = 0; e < 8; ++e) {
    int idx = e * 1024 + t * 4;            // 4 contiguous elems per thread
    int q = idx >> 6, d = idx & 63;
    float inv = rcpq(l0[q] + l1[q]);
    bf16x4 a = *(const bf16x4*)(o0 + idx);
    bf16x4 bb = *(const bf16x4*)(o1 + idx);
    bf16x4 r;
#pragma unroll
    for (int j = 0; j < 4; ++j) r[j] = (bf16)(((float)a[j] + (float)bb[j]) * inv);
    *(bf16x4*)(ATT + ((size_t)(b * 2048 + qt * 128 + q) * 1024) + h * 64 + d) = r;
  }
}

// ---------------------------------------------------------------------------
__global__ __launch_bounds__(256) void ln_k(const float* __restrict__ X,
                                            const float* __restrict__ g,
                                            const float* __restrict__ bta,
                                            bf16* __restrict__ outb,
                                            float* __restrict__ outf) {
  const int tid = threadIdx.x;
  const size_t row = blockIdx.x;
  const float* x = X + row * 1024;
  float4 v = *(const float4*)(x + tid * 4);
  float sum = v.x + v.y + v.z + v.w;
  float sq = v.x * v.x + v.y * v.y + v.z * v.z + v.w * v.w;
#pragma unroll
  for (int m = 1; m < 64; m <<= 1) {
    sum += __shfl_xor(sum, m);
    sq += __shfl_xor(sq, m);
  }
  __shared__ float s1[4], s2[4];
  int w = tid >> 6;
  if ((tid & 63) == 0) { s1[w] = sum; s2[w] = sq; }
  __syncthreads();
  sum = s1[0] + s1[1] + s1[2] + s1[3];
  sq = s2[0] + s2[1] + s2[2] + s2[3];
  float mean = sum * (1.f / 1024.f);
  float var = sq * (1.f / 1024.f) - mean * mean;
  float inv = rsqrtf(var + 1e-6f);
  float4 gv = *(const float4*)(g + tid * 4);
  float4 bv = *(const float4*)(bta + tid * 4);
  float y0 = (v.x - mean) * inv * gv.x + bv.x;
  float y1 = (v.y - mean) * inv * gv.y + bv.y;
  float y2 = (v.z - mean) * inv * gv.z + bv.z;
  float y3 = (v.w - mean) * inv * gv.w + bv.w;
  if (outb) {
    bf16x4 ob;
    ob[0] = (bf16)y0; ob[1] = (bf16)y1; ob[2] = (bf16)y2; ob[3] = (bf16)y3;
    *(bf16x4*)(outb + row * 1024 + tid * 4) = ob;
  }
  if (outf) {
    float4 of;
    of.x = y0; of.y = y1; of.z = y2; of.w = y3;
    *(float4*)(outf + row * 1024 + tid * 4) = of;
  }
}

// ---------------------------------------------------------------------------
extern "C" void kernel_launch(void* const* d_in, const int* in_sizes, int n_in,
                              void* d_out, int out_size, void* d_ws, size_t ws_size,
                              hipStream_t stream) {
  (void)in_sizes; (void)n_in; (void)out_size; (void)ws_size;
  const float* inp = (const float*)d_in[0];
  const float* ctx = (const float*)d_in[1];
  const float* Wk1 = (const float*)d_in[2];
  const float* Wv1 = (const float*)d_in[3];
  const float* Wq1 = (const float*)d_in[4];
  const float* Wo1 = (const float*)d_in[5];
  const float* bo1 = (const float*)d_in[6];
  const float* Wk2 = (const float*)d_in[7];
  const float* Wv2 = (const float*)d_in[8];
  const float* Wq2 = (const float*)d_in[9];
  const float* Wo2 = (const float*)d_in[10];
  const float* bo2 = (const float*)d_in[11];
  const float* Wf = (const float*)d_in[12];
  const float* bfp = (const float*)d_in[13];
  const float* g1 = (const float*)d_in[14];
  const float* b1 = (const float*)d_in[15];
  const float* g2 = (const float*)d_in[16];
  const float* b2 = (const float*)d_in[17];
  const float* g3 = (const float*)d_in[18];
  const float* b3 = (const float*)d_in[19];
  float* out = (float*)d_out;

  char* ws = (char*)d_ws;
  size_t off = 0;
  auto alloc = [&](size_t bytes) {
    char* p = ws + off;
    off += (bytes + 255) & ~(size_t)255;
    return p;
  };
  bf16* XB = (bf16*)alloc(4096ULL * 1024 * 2);       // inputs bf16; reused as AB
  bf16* CB = (bf16*)alloc(4096ULL * 1024 * 2);       // context bf16; reused as CBf
  bf16* WQKV1 = (bf16*)alloc(3072ULL * 1024 * 2);
  bf16* WO1 = (bf16*)alloc(1024ULL * 1024 * 2);
  bf16* WQ2 = (bf16*)alloc(1024ULL * 1024 * 2);
  bf16* WKV2 = (bf16*)alloc(2048ULL * 1024 * 2);
  bf16* WO2 = (bf16*)alloc(1024ULL * 1024 * 2);
  bf16* WFt = (bf16*)alloc(1024ULL * 1024 * 2);
  bf16* QKV1 = (bf16*)alloc(4096ULL * 3072 * 2);     // later: Q2 (first 8MB) + KV2 (next 16MB)
  bf16* V1T = (bf16*)alloc(32ULL * 64 * 2048 * 2);   // reused as V2T
  bf16* ATT1 = (bf16*)alloc(4096ULL * 1024 * 2);     // reused as ATT2
  float* T1 = (float*)alloc(4096ULL * 1024 * 4);     // reused as T2, T3
  float* CF = (float*)alloc(4096ULL * 1024 * 4);
  bf16* OPart = (bf16*)alloc(1024ULL * 8192 * 2);    // causal k-split partial O
  float* LPart = (float*)alloc(1024ULL * 128 * 4);   // causal k-split partial l

  bf16* AB = XB;
  bf16* CBf = CB;
  bf16* Q2 = QKV1;
  bf16* KV2 = QKV1 + 4096ULL * 1024;
  bf16* V2T = V1T;
  bf16* ATT2 = ATT1;
  float* T2 = T1;
  float* T3 = T1;

  dim3 b256(256);
  dim3 b512(512);

  // fused convert + all weight packs (one launch)
  prep_k<<<10496, b256, 0, stream>>>(inp, ctx, XB, CB,
                                     Wq1, Wk1, Wv1, Wq2, Wk2, Wv2,
                                     WQKV1, WQ2, WKV2,
                                     Wo1, Wo2, Wf, WO1, WO2, WFt);

  // ---- layer 1: masked self-attention (k-split + combine) ----
  gemm_qkv_k<<<dim3(24, 32), b256, 0, stream>>>(XB, WQKV1, QKV1, V1T, 3072, 1024, 2048);
  attn_k<1><<<dim3(32, 32), b512, 0, stream>>>(QKV1, 3072, (size_t)2048 * 3072,
                                               QKV1 + 1024, 3072, (size_t)2048 * 3072,
                                               V1T, ATT1, 1024, (size_t)2048 * 1024, 2048,
                                               OPart, LPart);
  combine_k<<<512, b256, 0, stream>>>(OPart, LPart, ATT1);
  gemm64_k<1><<<dim3(8, 64), b512, 0, stream>>>(ATT1, WO1, nullptr, T1, bo1, inp,
                                                1024, 1024, 1.f);
  ln_k<<<4096, b256, 0, stream>>>(T1, g1, b1, AB, nullptr);

  // ---- layer 2: cross-attention (Q from a, K/V from context), merged GEMM ----
  gemm_bt2_k<<<dim3(24, 32), b256, 0, stream>>>(AB, WQ2, Q2, CB, WKV2, KV2, V2T, 1024);
  attn_k<0><<<dim3(16, 32), b512, 0, stream>>>(Q2, 1024, (size_t)2048 * 1024,
                                               KV2, 2048, (size_t)2048 * 2048,
                                               V2T, ATT2, 1024, (size_t)2048 * 1024, 2048,
                                               nullptr, nullptr);
  gemm64_k<1><<<dim3(8, 64), b512, 0, stream>>>(ATT2, WO2, nullptr, T2, bo2, nullptr,
                                                1024, 1024, 2.f);
  ln_k<<<4096, b256, 0, stream>>>(T2, g2, b2, CBf, CF);

  // ---- FFN + final LN ----
  gemm64_k<1><<<dim3(8, 64), b512, 0, stream>>>(CBf, WFt, nullptr, T3, bfp, CF,
                                                1024, 1024, 1.f);
  ln_k<<<4096, b256, 0, stream>>>(T3, g3, b3, nullptr, out);
}

// Round 20
// 218.186 us; speedup vs baseline: 1.0700x; 1.0394x over previous
//
#include <hip/hip_runtime.h>
#include <stdint.h>
#include <stddef.h>

typedef __bf16 bf16;
typedef __bf16 bf16x8 __attribute__((ext_vector_type(8)));
typedef __bf16 bf16x4 __attribute__((ext_vector_type(4)));
typedef float  f32x4  __attribute__((ext_vector_type(4)));
typedef uint32_t u32x4 __attribute__((ext_vector_type(4)));

#define MFMA(a, b, c) __builtin_amdgcn_mfma_f32_16x16x32_bf16((a), (b), (c), 0, 0, 0)
// element offset of (row, 16B-chunk) in a swizzled [*][64] bf16 tile
#define SWZE(row, chunk) (((row) << 6) + ((((chunk) ^ ((row) & 7))) << 3))

static __device__ __forceinline__ void gload_lds16(const void* g, void* l) {
  __builtin_amdgcn_global_load_lds((const __attribute__((address_space(1))) void*)g,
                                   (__attribute__((address_space(3))) void*)l,
                                   16, 0, 0);
}
static __device__ __forceinline__ void waitvm0() {
  asm volatile("s_waitcnt vmcnt(0)" ::: "memory");
}
static __device__ __forceinline__ float expq(float x) {  // raw v_exp_f32 (2^x)
  float r;
  asm("v_exp_f32 %0, %1" : "=v"(r) : "v"(x));
  return r;
}
static __device__ __forceinline__ float rcpq(float x) {
  float r;
  asm("v_rcp_f32 %0, %1" : "=v"(r) : "v"(x));
  return r;
}
static __device__ __forceinline__ uint32_t cvtpk_bf16(float lo, float hi) {
  uint32_t r;
  asm("v_cvt_pk_bf16_f32 %0, %1, %2" : "=v"(r) : "v"(lo), "v"(hi));
  return r;
}
// bijective XCD swizzle (requires nwg % 8 == 0)
static __device__ __forceinline__ int xcd_swz(int orig, int nwg) {
  return (orig & 7) * (nwg >> 3) + (orig >> 3);
}
// V^T k-permutation within each 32-block: staged slot t holds V row
// k_phys(t) = t2<<4 | t4<<3 | t3<<2 | t1<<1 | t0. Inverse (store side):
// row s goes to slot (s&~31) | s3<<4 | s2<<3 | s4<<2 | (s&3)
static __device__ __forceinline__ int vperm_store(int s) {
  return (s & ~31) | (((s >> 3) & 1) << 4) | (((s >> 2) & 1) << 3) |
         (((s >> 4) & 1) << 2) | (s & 3);
}

// ---------------------------------------------------------------------------
// prep_k: fused input-convert + all weight packing (one launch).
__global__ __launch_bounds__(256) void prep_k(
    const float* __restrict__ inp, const float* __restrict__ ctx,
    bf16* __restrict__ XB, bf16* __restrict__ CB,
    const float* __restrict__ Wq1, const float* __restrict__ Wk1,
    const float* __restrict__ Wv1, const float* __restrict__ Wq2,
    const float* __restrict__ Wk2, const float* __restrict__ Wv2,
    bf16* __restrict__ WQKV1, bf16* __restrict__ WQ2, bf16* __restrict__ WKV2,
    const float* __restrict__ Wo1, const float* __restrict__ Wo2,
    const float* __restrict__ Wf,
    bf16* __restrict__ WO1, bf16* __restrict__ WO2, bf16* __restrict__ WFt) {
  const int tid = threadIdx.x;
  int bx = blockIdx.x;
  if (bx < 8192) {
    const float* s = bx < 4096 ? inp : ctx;
    bf16* d = bx < 4096 ? XB : CB;
    size_t idx = (size_t)(bx & 4095) * 256 + tid;
    float4 v = *(const float4*)(s + idx * 4);
    bf16x4 o;
    o[0] = (bf16)v.x; o[1] = (bf16)v.y; o[2] = (bf16)v.z; o[3] = (bf16)v.w;
    *(bf16x4*)(d + idx * 4) = o;
    return;
  }
  bx -= 8192;
  __shared__ float T[64][65];
  if (bx < 1536) {
    const int wi = bx >> 8, sub = bx & 255;
    const float* src = (wi == 0) ? Wq1 : (wi == 1) ? Wk1 : (wi == 2) ? Wv1
                     : (wi == 3) ? Wq2 : (wi == 4) ? Wk2 : Wv2;
    bf16* dst = (wi == 0) ? WQKV1 : (wi == 1) ? WQKV1 + 1048576
              : (wi == 2) ? WQKV1 + 2097152 : (wi == 3) ? WQ2
              : (wi == 4) ? WKV2 : WKV2 + 1048576;
    const int e0 = (sub & 15) * 64, h = sub >> 4;
    const int er = tid >> 4, dof = (tid & 15) * 4;
#pragma unroll
    for (int i = 0; i < 4; ++i) {
      int e = i * 16 + er;
      float4 v = *(const float4*)(src + ((size_t)h * 1024 + e0 + e) * 64 + dof);
      T[e][dof] = v.x; T[e][dof + 1] = v.y; T[e][dof + 2] = v.z; T[e][dof + 3] = v.w;
    }
    __syncthreads();
    const int dr = tid >> 3, eo = (tid & 7) * 8;
#pragma unroll
    for (int i = 0; i < 2; ++i) {
      int d = i * 32 + dr;
      bf16x8 ov;
#pragma unroll
      for (int j = 0; j < 8; ++j) ov[j] = (bf16)T[eo + j][d];
      *(bf16x8*)(dst + ((size_t)h * 64 + d) * 1024 + e0 + eo) = ov;
    }
    return;
  }
  bx -= 1536;
  {
    const int wi = bx >> 8, sub = bx & 255;
    const float* src = (wi == 0) ? Wo1 : (wi == 1) ? Wo2 : Wf;
    bf16* dst = (wi == 0) ? WO1 : (wi == 1) ? WO2 : WFt;
    const int k0 = (sub & 15) * 64, n0 = (sub >> 4) * 64;
    const int kr = tid >> 4, no = (tid & 15) * 4;
#pragma unroll
    for (int i = 0; i < 4; ++i) {
      int k = i * 16 + kr;
      float4 v = *(const float4*)(src + (size_t)(k0 + k) * 1024 + n0 + no);
      T[k][no] = v.x; T[k][no + 1] = v.y; T[k][no + 2] = v.z; T[k][no + 3] = v.w;
    }
    __syncthreads();
    const int nr = tid >> 3, ko = (tid & 7) * 8;
#pragma unroll
    for (int i = 0; i < 2; ++i) {
      int n = i * 32 + nr;
      bf16x8 ov;
#pragma unroll
      for (int j = 0; j < 8; ++j) ov[j] = (bf16)T[ko + j][n];
      *(bf16x8*)(dst + (size_t)(n0 + n) * 1024 + k0 + ko) = ov;
    }
  }
}

// ---------------------------------------------------------------------------
// 128x128 GEMM body, XOR-swizzled LDS tiles (conflict-free ds_read_b128).
// EPI 0: Cb = (bf16)acc
// EPI 1: Cf = mul*relu(acc+bias[col]) + resid
// EPI 2: like 0, but blocks with n0 >= colV write TRANSPOSED + k-PERMUTED into Vt
template <int EPI>
static __device__ __forceinline__ void gemm_body(
    const bf16* __restrict__ A, const bf16* __restrict__ Bt,
    bf16* __restrict__ Cb, float* __restrict__ Cf,
    const float* __restrict__ bias, const float* __restrict__ resid,
    int N, int K, float mul, int m0, int n0, bf16* As, bf16* Bs,
    bf16* __restrict__ Vt, int colV) {
  const int tid = threadIdx.x;
  const int l = tid & 63, w = tid >> 6;
  const int l15 = l & 15, g4 = l >> 4;
  const int wr = w >> 1, wc = w & 1;
  f32x4 acc[4][4] = {};
  const int crow = tid >> 3, sj = tid & 7;
  for (int k0 = 0; k0 < K; k0 += 64) {
#pragma unroll
    for (int i = 0; i < 4; ++i) {
      int row = i * 32 + crow;
      int je = ((sj ^ (row & 7)) << 3);   // pre-swizzled source chunk
      gload_lds16(A + (size_t)(m0 + row) * K + (k0 + je), (char*)As + (i * 256 + tid) * 16);
      gload_lds16(Bt + (size_t)(n0 + row) * K + (k0 + je), (char*)Bs + (i * 256 + tid) * 16);
    }
    __syncthreads();
#pragma unroll
    for (int kk = 0; kk < 2; ++kk) {
      bf16x8 af[4], bfr[4];
#pragma unroll
      for (int x = 0; x < 4; ++x) {
        af[x]  = *(const bf16x8*)&As[SWZE(wr * 64 + x * 16 + l15, kk * 4 + g4)];
        bfr[x] = *(const bf16x8*)&Bs[SWZE(wc * 64 + x * 16 + l15, kk * 4 + g4)];
      }
      __builtin_amdgcn_s_setprio(1);
#pragma unroll
      for (int mf = 0; mf < 4; ++mf)
#pragma unroll
        for (int nf = 0; nf < 4; ++nf)
          acc[mf][nf] = MFMA(af[mf], bfr[nf], acc[mf][nf]);
      __builtin_amdgcn_s_setprio(0);
    }
    __syncthreads();
  }
  if (EPI == 2 && n0 >= colV) {
#pragma unroll
    for (int mf = 0; mf < 4; ++mf)
#pragma unroll
      for (int nf = 0; nf < 4; ++nf) {
        int colrel = n0 + wc * 64 + nf * 16 + l15 - colV;
        int h = colrel >> 6, d = colrel & 63;
        int row = m0 + wr * 64 + mf * 16 + g4 * 4;
        int b = row >> 11, s = row & 2047;
        bf16x4 pv;
#pragma unroll
        for (int r = 0; r < 4; ++r) pv[r] = (bf16)acc[mf][nf][r];
        *(bf16x4*)(Vt + (((size_t)(b * 16 + h) * 64 + d) * 2048 + vperm_store(s))) = pv;
      }
    return;
  }
#pragma unroll
  for (int mf = 0; mf < 4; ++mf)
#pragma unroll
    for (int nf = 0; nf < 4; ++nf)
#pragma unroll
      for (int r = 0; r < 4; ++r) {
        int row = m0 + wr * 64 + mf * 16 + g4 * 4 + r;
        int col = n0 + wc * 64 + nf * 16 + l15;
        size_t idx = (size_t)row * N + col;
        float v = acc[mf][nf][r];
        if (EPI == 1) {
          v = mul * fmaxf(v + bias[col], 0.f);
          if (resid) v += resid[idx];
          Cf[idx] = v;
        } else {
          Cb[idx] = (bf16)v;
        }
      }
}

// QKV projection GEMM (N=3072), V block-columns written transposed to Vt
__global__ __launch_bounds__(256) void gemm_qkv_k(
    const bf16* __restrict__ A, const bf16* __restrict__ Bt,
    bf16* __restrict__ Cb, bf16* __restrict__ Vt, int N, int K, int colV) {
  __shared__ __align__(16) bf16 As[128 * 64];
  __shared__ __align__(16) bf16 Bs[128 * 64];
  int swz = xcd_swz(blockIdx.y * gridDim.x + blockIdx.x, gridDim.x * gridDim.y);
  int bx = swz % gridDim.x, by = swz / gridDim.x;
  gemm_body<2>(A, Bt, Cb, nullptr, nullptr, nullptr, N, K, 1.f,
               by * 128, bx * 128, As, Bs, Vt, colV);
}

// Merged dispatch for layer 2: x<8 -> Q2 (N=1024), else KV2 (N=2048, V->V2T)
__global__ __launch_bounds__(256) void gemm_bt2_k(
    const bf16* __restrict__ A0, const bf16* __restrict__ Bt0, bf16* __restrict__ C0,
    const bf16* __restrict__ A1, const bf16* __restrict__ Bt1, bf16* __restrict__ C1,
    bf16* __restrict__ Vt, int K) {
  __shared__ __align__(16) bf16 As[128 * 64];
  __shared__ __align__(16) bf16 Bs[128 * 64];
  int swz = xcd_swz(blockIdx.y * gridDim.x + blockIdx.x, gridDim.x * gridDim.y);
  int bx = swz % gridDim.x, by = swz / gridDim.x;
  if (bx < 8)
    gemm_body<0>(A0, Bt0, C0, nullptr, nullptr, nullptr, 1024, K, 1.f,
                 by * 128, bx * 128, As, Bs, nullptr, 1 << 30);
  else
    gemm_body<2>(A1, Bt1, C1, nullptr, nullptr, nullptr, 2048, K, 1.f,
                 by * 128, (bx - 8) * 128, As, Bs, Vt, 1024);
}

// ---------------------------------------------------------------------------
// 64x128 GEMM for small-N shapes, 512 threads / 8 waves (2 Mx4 N), each wave
// 32x32 output, XOR-swizzled LDS. grid (N/128, M/64) = 512 blocks.
template <int EPI>
__global__ __launch_bounds__(512) void gemm64_k(
    const bf16* __restrict__ A, const bf16* __restrict__ Bt,
    bf16* __restrict__ Cb, float* __restrict__ Cf,
    const float* __restrict__ bias, const float* __restrict__ resid,
    int N, int K, float mul) {
  __shared__ __align__(16) bf16 As[64 * 64];
  __shared__ __align__(16) bf16 Bs[128 * 64];
  const int tid = threadIdx.x;
  const int l = tid & 63, w = tid >> 6;   // 8 waves
  const int l15 = l & 15, g4 = l >> 4;
  const int wr = w >> 2, wc = w & 3;      // 2 (M) x 4 (N)
  int swz = xcd_swz(blockIdx.y * gridDim.x + blockIdx.x, gridDim.x * gridDim.y);
  const int m0 = (swz / gridDim.x) * 64, n0 = (swz % gridDim.x) * 128;
  f32x4 acc[2][2] = {};
  const int crow = tid >> 3, sj = tid & 7;  // crow 0..63
  const int jeA = ((sj ^ (crow & 7)) << 3);
  for (int k0 = 0; k0 < K; k0 += 64) {
    gload_lds16(A + (size_t)(m0 + crow) * K + (k0 + jeA), (char*)As + tid * 16);
#pragma unroll
    for (int i = 0; i < 2; ++i) {
      int row = i * 64 + crow;
      int je = ((sj ^ (row & 7)) << 3);
      gload_lds16(Bt + (size_t)(n0 + row) * K + (k0 + je), (char*)Bs + (i * 512 + tid) * 16);
    }
    __syncthreads();
#pragma unroll
    for (int kk = 0; kk < 2; ++kk) {
      bf16x8 af[2], bfr[2];
#pragma unroll
      for (int x = 0; x < 2; ++x) {
        af[x]  = *(const bf16x8*)&As[SWZE(wr * 32 + x * 16 + l15, kk * 4 + g4)];
        bfr[x] = *(const bf16x8*)&Bs[SWZE(wc * 32 + x * 16 + l15, kk * 4 + g4)];
      }
      __builtin_amdgcn_s_setprio(1);
#pragma unroll
      for (int mf = 0; mf < 2; ++mf)
#pragma unroll
        for (int nf = 0; nf < 2; ++nf)
          acc[mf][nf] = MFMA(af[mf], bfr[nf], acc[mf][nf]);
      __builtin_amdgcn_s_setprio(0);
    }
    __syncthreads();
  }
#pragma unroll
  for (int mf = 0; mf < 2; ++mf)
#pragma unroll
    for (int nf = 0; nf < 2; ++nf)
#pragma unroll
      for (int r = 0; r < 4; ++r) {
        int row = m0 + wr * 32 + mf * 16 + g4 * 4 + r;
        int col = n0 + wc * 32 + nf * 16 + l15;
        size_t idx = (size_t)row * N + col;
        float v = acc[mf][nf][r];
        if (EPI == 0) {
          Cb[idx] = (bf16)v;
        } else {
          v = mul * fmaxf(v + bias[col], 0.f);
          if (resid) v += resid[idx];
          Cf[idx] = v;
        }
      }
}

// ---------------------------------------------------------------------------
// Flash attention, 128 q-rows/block (8 waves, 512 thr), 32KB LDS, 2-deep
// staging. Waves (qh in 4, kh in 2) = 32q x 32k. No max tracking (|s|<1);
// V^T k-permuted so PV A-frag is pure per-lane repack; row-sum via ones-MFMA;
// kh-reduction via 2-phase LDS scratch.
// CAUSAL: q-tile qt covers chunks [0, 2qt+1]; grid 512, slot-complementary.
template <int CAUSAL>
__global__ __launch_bounds__(512) void attn_k(
    const bf16* __restrict__ Q, int ldq, size_t sBq,
    const bf16* __restrict__ Kp, int ldk, size_t sBk,
    const bf16* __restrict__ Vt,
    bf16* __restrict__ O, int ldo, size_t sBo,
    int Sk) {
  __shared__ __align__(16) char smem[32768];   // Ks[2][8KB] | Vs[2][8KB]; reused as scratch
  bf16* const KsBase = (bf16*)smem;
  bf16* const VsBase = (bf16*)(smem + 16384);
  const int tid = threadIdx.x;
  const int l = tid & 63, w = tid >> 6;   // 8 waves
  const int l15 = l & 15, g4 = l >> 4;
  const int qh = w >> 1, kh = w & 1;      // 4 q-quarters x 2 k-halves
  const int orig = blockIdx.y * gridDim.x + blockIdx.x;
  int qt, bh;
  if (CAUSAL) {
    // 512 blocks; per-CU complementary lengths: slots {0,1} get {pb, 15-pb}
    const int slot = orig >> 8, s = orig & 255;
    const int pb = s & 15;
    qt = slot ? (15 - pb) : pb;
    bh = (s >> 4) * 2 + slot;
  } else {
    const int swz = xcd_swz(orig, gridDim.x * gridDim.y);
    qt = swz % gridDim.x;
    bh = swz / gridDim.x;
  }
  const int b = bh >> 4, h = bh & 15;
  const int nT = Sk >> 6;
  const int total = CAUSAL ? (2 * qt + 2) : nT;
  const int q0b = qt * 128;
  const int qw = q0b + qh * 32;           // wave's q-base
  const bf16* Qb = Q + (size_t)b * sBq + h * 64;
  const bf16* Kb = Kp + (size_t)b * sBk + h * 64;
  const bf16* Vb = Vt + ((size_t)bh * 64) * Sk;
  bf16* Ob = O + (size_t)b * sBo + h * 64;
  const float sc2 = rsqrtf((float)Sk) * 1.442695040888963f;  // 1/sqrt(Sk)*log2(e)

  // Q rows for this wave (32 rows), pre-scaled
  bf16x8 qf[2][2];
#pragma unroll
  for (int qg = 0; qg < 2; ++qg)
#pragma unroll
    for (int kk = 0; kk < 2; ++kk) {
      bf16x8 t8 = *(const bf16x8*)(Qb + (size_t)(qw + qg * 16 + l15) * ldq + kk * 32 + g4 * 8);
#pragma unroll
      for (int j = 0; j < 8; ++j) t8[j] = (bf16)((float)t8[j] * sc2);
      qf[qg][kk] = t8;
    }

  bf16x8 onesb;
#pragma unroll
  for (int j = 0; j < 8; ++j) onesb[j] = (bf16)1.0f;

  // o[qg][nf2]: partial O for q = qw+qg*16+g4*4+r, d = nf2*16+l15 (k-half kh)
  f32x4 o[2][4] = {};
  f32x4 ol[2] = {};

  // 512 threads stage 16KB: 1 K-load + 1 V-load per thread per chunk.
  const int srow = tid >> 3, sj = tid & 7;   // srow 0..63
  const int je = ((sj ^ (srow & 7)) << 3);
  auto stage = [&](int ch, int bufi) {
    gload_lds16(Kb + (size_t)(ch * 64 + srow) * ldk + je,
                (char*)(KsBase + bufi * 4096) + tid * 16);
    gload_lds16(Vb + (size_t)srow * Sk + ch * 64 + je,
                (char*)(VsBase + bufi * 4096) + tid * 16);
  };

  stage(0, 0);
  waitvm0();
  __builtin_amdgcn_s_barrier();

  int cur = 0;

  for (int i = 0; i < total; ++i) {
    if (i + 1 < total) stage(i + 1, cur ^ 1);

    const int k0 = i * 64;
    const bf16* ks = KsBase + cur * 4096;
    const bf16* vs = VsBase + cur * 4096;

    // S^T[k = kh*32+ksub*16+g4*4+r][q(qg) = l15] = mfma(A=K-half, B=Q^T)
    f32x4 s[2][2] = {};
    __builtin_amdgcn_s_setprio(1);
#pragma unroll
    for (int ksub = 0; ksub < 2; ++ksub)
#pragma unroll
      for (int kk = 0; kk < 2; ++kk) {
        bf16x8 kf = *(const bf16x8*)&ks[SWZE(kh * 32 + ksub * 16 + l15, kk * 4 + g4)];
        s[ksub][0] = MFMA(kf, qf[0][kk], s[ksub][0]);
        s[ksub][1] = MFMA(kf, qf[1][kk], s[ksub][1]);
      }
    __builtin_amdgcn_s_setprio(0);

    if (CAUSAL && i >= total - 2) {  // last two chunks straddle the diagonal
#pragma unroll
      for (int ksub = 0; ksub < 2; ++ksub)
#pragma unroll
        for (int qg = 0; qg < 2; ++qg)
#pragma unroll
          for (int r = 0; r < 4; ++r)
            if ((k0 + kh * 32 + ksub * 16 + g4 * 4 + r) > (qw + qg * 16 + l15))
              s[ksub][qg][r] = -3e38f;
    }

    // P = exp2(s) directly (masked -> 0)
#pragma unroll
    for (int ksub = 0; ksub < 2; ++ksub)
#pragma unroll
      for (int qg = 0; qg < 2; ++qg) {
        s[ksub][qg][0] = expq(s[ksub][qg][0]);
        s[ksub][qg][1] = expq(s[ksub][qg][1]);
        s[ksub][qg][2] = expq(s[ksub][qg][2]);
        s[ksub][qg][3] = expq(s[ksub][qg][3]);
      }

    // V^T fragments for this k-half (shared by both q-groups): 4 b128 reads
    bf16x8 vf[4];
#pragma unroll
    for (int nf2 = 0; nf2 < 4; ++nf2)
      vf[nf2] = *(const bf16x8*)&vs[SWZE(nf2 * 16 + l15, kh * 4 + g4)];

    __builtin_amdgcn_s_setprio(1);
#pragma unroll
    for (int qg = 0; qg < 2; ++qg) {
      u32x4 td;
      td[0] = cvtpk_bf16(s[0][qg][0], s[0][qg][1]);
      td[1] = cvtpk_bf16(s[0][qg][2], s[0][qg][3]);
      td[2] = cvtpk_bf16(s[1][qg][0], s[1][qg][1]);
      td[3] = cvtpk_bf16(s[1][qg][2], s[1][qg][3]);
      bf16x8 pa = __builtin_bit_cast(bf16x8, td);
#pragma unroll
      for (int nf2 = 0; nf2 < 4; ++nf2)
        o[qg][nf2] = MFMA(pa, vf[nf2], o[qg][nf2]);
      ol[qg] = MFMA(pa, onesb, ol[qg]);
    }
    __builtin_amdgcn_s_setprio(0);

    waitvm0();
    __builtin_amdgcn_s_barrier();
    cur ^= 1;
  }

  // Cross-wave reduction over kh (partner waves share qh), 2 phases (one per
  // qg) through 21KB LDS scratch (stride 21 floats per lane, conflict-light).
  {
    float* sc = (float*)smem;
    float* my = sc + (size_t)(qh * 64 + l) * 21;
#pragma unroll
    for (int qg = 0; qg < 2; ++qg) {
      __syncthreads();
      if (kh == 1) {
#pragma unroll
        for (int nf2 = 0; nf2 < 4; ++nf2)
#pragma unroll
          for (int r = 0; r < 4; ++r) my[nf2 * 4 + r] = o[qg][nf2][r];
#pragma unroll
        for (int r = 0; r < 4; ++r) my[16 + r] = ol[qg][r];
      }
      __syncthreads();
      if (kh == 0) {
        float inv[4];
#pragma unroll
        for (int r = 0; r < 4; ++r) inv[r] = rcpq(ol[qg][r] + my[16 + r]);
#pragma unroll
        for (int nf2 = 0; nf2 < 4; ++nf2)
#pragma unroll
          for (int r = 0; r < 4; ++r) {
            float v = (o[qg][nf2][r] + my[nf2 * 4 + r]) * inv[r];
            Ob[(size_t)(qw + qg * 16 + g4 * 4 + r) * ldo + nf2 * 16 + l15] = (bf16)v;
          }
      }
    }
  }
}

// ---------------------------------------------------------------------------
__global__ __launch_bounds__(256) void ln_k(const float* __restrict__ X,
                                            const float* __restrict__ g,
                                            const float* __restrict__ bta,
                                            bf16* __restrict__ outb,
                                            float* __restrict__ outf) {
  const int tid = threadIdx.x;
  const size_t row = blockIdx.x;
  const float* x = X + row * 1024;
  float4 v = *(const float4*)(x + tid * 4);
  float sum = v.x + v.y + v.z + v.w;
  float sq = v.x * v.x + v.y * v.y + v.z * v.z + v.w * v.w;
#pragma unroll
  for (int m = 1; m < 64; m <<= 1) {
    sum += __shfl_xor(sum, m);
    sq += __shfl_xor(sq, m);
  }
  __shared__ float s1[4], s2[4];
  int w = tid >> 6;
  if ((tid & 63) == 0) { s1[w] = sum; s2[w] = sq; }
  __syncthreads();
  sum = s1[0] + s1[1] + s1[2] + s1[3];
  sq = s2[0] + s2[1] + s2[2] + s2[3];
  float mean = sum * (1.f / 1024.f);
  float var = sq * (1.f / 1024.f) - mean * mean;
  float inv = rsqrtf(var + 1e-6f);
  float4 gv = *(const float4*)(g + tid * 4);
  float4 bv = *(const float4*)(bta + tid * 4);
  float y0 = (v.x - mean) * inv * gv.x + bv.x;
  float y1 = (v.y - mean) * inv * gv.y + bv.y;
  float y2 = (v.z - mean) * inv * gv.z + bv.z;
  float y3 = (v.w - mean) * inv * gv.w + bv.w;
  if (outb) {
    bf16x4 ob;
    ob[0] = (bf16)y0; ob[1] = (bf16)y1; ob[2] = (bf16)y2; ob[3] = (bf16)y3;
    *(bf16x4*)(outb + row * 1024 + tid * 4) = ob;
  }
  if (outf) {
    float4 of;
    of.x = y0; of.y = y1; of.z = y2; of.w = y3;
    *(float4*)(outf + row * 1024 + tid * 4) = of;
  }
}

// ---------------------------------------------------------------------------
extern "C" void kernel_launch(void* const* d_in, const int* in_sizes, int n_in,
                              void* d_out, int out_size, void* d_ws, size_t ws_size,
                              hipStream_t stream) {
  (void)in_sizes; (void)n_in; (void)out_size; (void)ws_size;
  const float* inp = (const float*)d_in[0];
  const float* ctx = (const float*)d_in[1];
  const float* Wk1 = (const float*)d_in[2];
  const float* Wv1 = (const float*)d_in[3];
  const float* Wq1 = (const float*)d_in[4];
  const float* Wo1 = (const float*)d_in[5];
  const float* bo1 = (const float*)d_in[6];
  const float* Wk2 = (const float*)d_in[7];
  const float* Wv2 = (const float*)d_in[8];
  const float* Wq2 = (const float*)d_in[9];
  const float* Wo2 = (const float*)d_in[10];
  const float* bo2 = (const float*)d_in[11];
  const float* Wf = (const float*)d_in[12];
  const float* bfp = (const float*)d_in[13];
  const float* g1 = (const float*)d_in[14];
  const float* b1 = (const float*)d_in[15];
  const float* g2 = (const float*)d_in[16];
  const float* b2 = (const float*)d_in[17];
  const float* g3 = (const float*)d_in[18];
  const float* b3 = (const float*)d_in[19];
  float* out = (float*)d_out;

  char* ws = (char*)d_ws;
  size_t off = 0;
  auto alloc = [&](size_t bytes) {
    char* p = ws + off;
    off += (bytes + 255) & ~(size_t)255;
    return p;
  };
  bf16* XB = (bf16*)alloc(4096ULL * 1024 * 2);       // inputs bf16; reused as AB
  bf16* CB = (bf16*)alloc(4096ULL * 1024 * 2);       // context bf16; reused as CBf
  bf16* WQKV1 = (bf16*)alloc(3072ULL * 1024 * 2);
  bf16* WO1 = (bf16*)alloc(1024ULL * 1024 * 2);
  bf16* WQ2 = (bf16*)alloc(1024ULL * 1024 * 2);
  bf16* WKV2 = (bf16*)alloc(2048ULL * 1024 * 2);
  bf16* WO2 = (bf16*)alloc(1024ULL * 1024 * 2);
  bf16* WFt = (bf16*)alloc(1024ULL * 1024 * 2);
  bf16* QKV1 = (bf16*)alloc(4096ULL * 3072 * 2);     // later: Q2 (first 8MB) + KV2 (next 16MB)
  bf16* V1T = (bf16*)alloc(32ULL * 64 * 2048 * 2);   // reused as V2T
  bf16* ATT1 = (bf16*)alloc(4096ULL * 1024 * 2);     // reused as ATT2
  float* T1 = (float*)alloc(4096ULL * 1024 * 4);     // reused as T2, T3
  float* CF = (float*)alloc(4096ULL * 1024 * 4);

  bf16* AB = XB;
  bf16* CBf = CB;
  bf16* Q2 = QKV1;
  bf16* KV2 = QKV1 + 4096ULL * 1024;
  bf16* V2T = V1T;
  bf16* ATT2 = ATT1;
  float* T2 = T1;
  float* T3 = T1;

  dim3 b256(256);
  dim3 b512(512);

  // fused convert + all weight packs (one launch)
  prep_k<<<10496, b256, 0, stream>>>(inp, ctx, XB, CB,
                                     Wq1, Wk1, Wv1, Wq2, Wk2, Wv2,
                                     WQKV1, WQ2, WKV2,
                                     Wo1, Wo2, Wf, WO1, WO2, WFt);

  // ---- layer 1: masked self-attention ----
  gemm_qkv_k<<<dim3(24, 32), b256, 0, stream>>>(XB, WQKV1, QKV1, V1T, 3072, 1024, 2048);
  attn_k<1><<<dim3(16, 32), b512, 0, stream>>>(QKV1, 3072, (size_t)2048 * 3072,
                                               QKV1 + 1024, 3072, (size_t)2048 * 3072,
                                               V1T, ATT1, 1024, (size_t)2048 * 1024, 2048);
  gemm64_k<1><<<dim3(8, 64), b512, 0, stream>>>(ATT1, WO1, nullptr, T1, bo1, inp,
                                                1024, 1024, 1.f);
  ln_k<<<4096, b256, 0, stream>>>(T1, g1, b1, AB, nullptr);

  // ---- layer 2: cross-attention (Q from a, K/V from context), merged GEMM ----
  gemm_bt2_k<<<dim3(24, 32), b256, 0, stream>>>(AB, WQ2, Q2, CB, WKV2, KV2, V2T, 1024);
  attn_k<0><<<dim3(16, 32), b512, 0, stream>>>(Q2, 1024, (size_t)2048 * 1024,
                                               KV2, 2048, (size_t)2048 * 2048,
                                               V2T, ATT2, 1024, (size_t)2048 * 1024, 2048);
  gemm64_k<1><<<dim3(8, 64), b512, 0, stream>>>(ATT2, WO2, nullptr, T2, bo2, nullptr,
                                                1024, 1024, 2.f);
  ln_k<<<4096, b256, 0, stream>>>(T2, g2, b2, CBf, CF);

  // ---- FFN + final LN ----
  gemm64_k<1><<<dim3(8, 64), b512, 0, stream>>>(CBf, WFt, nullptr, T3, bfp, CF,
                                                1024, 1024, 1.f);
  ln_k<<<4096, b256, 0, stream>>>(T3, g3, b3, nullptr, out);
}